// Round 2
// baseline (312.616 us; speedup 1.0000x reference)
//
#include <hip/hip_runtime.h>

// SMPL forward, all I/O fp32. B=512, V=6890, J=24, NS=10, NP=207.
//
//  K1 k_jreg : JT = J_regressor @ v_template (24x3), JS = J_regressor @ shapedirs (24x3x10)
//  K2 k_chain: per-batch Rodrigues, Jrest, kinematic chain, A, G = rot_global @ A (3x4),
//              pose_feature (207) -> ws
//  K3 k_main : per (vertex, 8 batches): v_shaped + posedirs offset + LBS blend + Th -> out

#define BN 512
#define NV 6890
#define NJ 24
#define NS 10
#define NP 207
#define PSTR 208   // padded pose-feature stride (float4-aligned)
#define BB 8       // batches per block in k_main
#define TV 256     // vertices per block in k_main

// ws layout (floats): total ~1.02 MB
#define WS_JS 0                     // 24*33 = 792
#define WS_G  1024                  // 512*288 = 147456
#define WS_PF (1024 + BN*288)       // 512*208 = 106496

__constant__ int c_par[NJ] = {-1,0,0,0,1,2,3,4,5,6,7,8,9,9,9,12,13,14,16,17,18,19,20,21};

// ---------------- K1: fold J_regressor through template & shapedirs ----------------
__global__ __launch_bounds__(256) void k_jreg(const float* __restrict__ jreg,
                                              const float* __restrict__ vt,
                                              const float* __restrict__ sd,
                                              float* __restrict__ ws){
    int j = blockIdx.x;
    int tid = threadIdx.x;
    float acc[33];
    #pragma unroll
    for(int k=0;k<33;k++) acc[k]=0.f;
    for(int v=tid; v<NV; v+=256){
        float jr = jreg[j*NV+v];
        #pragma unroll
        for(int d=0;d<3;d++) acc[d] = fmaf(jr, vt[v*3+d], acc[d]);
        const float2* sp = (const float2*)(sd + (size_t)v*30);
        #pragma unroll
        for(int k=0;k<15;k++){
            float2 s2 = sp[k];
            acc[3+2*k]   = fmaf(jr, s2.x, acc[3+2*k]);
            acc[3+2*k+1] = fmaf(jr, s2.y, acc[3+2*k+1]);
        }
    }
    __shared__ float red[4][33];
    int lane = tid & 63, wv = tid >> 6;
    #pragma unroll
    for(int k=0;k<33;k++){
        float val = acc[k];
        #pragma unroll
        for(int off=32; off; off>>=1) val += __shfl_down(val, off, 64);
        if(lane==0) red[wv][k]=val;
    }
    __syncthreads();
    if(tid<33) ws[WS_JS + j*33 + tid] = red[0][tid]+red[1][tid]+red[2][tid]+red[3][tid];
}

// ---------------- K2: per-batch rodrigues + chain + G ----------------
__global__ __launch_bounds__(64) void k_chain(const float* __restrict__ poses,
                                              const float* __restrict__ shapes,
                                              const float* __restrict__ Rh,
                                              float* __restrict__ ws){
    int b = blockIdx.x;
    int t = threadIdx.x;
    __shared__ float R[25][9];     // [24] = global rotation from Rh
    __shared__ float sh[NS];
    __shared__ float jrest[NJ][3];
    __shared__ float rel[NJ][3];
    __shared__ float chR[NJ][9];
    __shared__ float chT[NJ][3];

    if(t<25){
        float x,y,z;
        if(t<24){ x=poses[b*72+t*3]; y=poses[b*72+t*3+1]; z=poses[b*72+t*3+2]; }
        else    { x=Rh[b*3];         y=Rh[b*3+1];         z=Rh[b*3+2]; }
        float ax=x+1e-8f, ay=y+1e-8f, az=z+1e-8f;
        float ang = sqrtf(ax*ax+ay*ay+az*az);
        float inv = 1.f/ang;
        float rx=x*inv, ry=y*inv, rz=z*inv;
        float s = sinf(ang), c = cosf(ang), oc = 1.f - c;
        R[t][0]=1.f+oc*(-rz*rz-ry*ry); R[t][1]=-s*rz+oc*(rx*ry);      R[t][2]= s*ry+oc*(rx*rz);
        R[t][3]= s*rz+oc*(rx*ry);      R[t][4]=1.f+oc*(-rz*rz-rx*rx); R[t][5]=-s*rx+oc*(ry*rz);
        R[t][6]=-s*ry+oc*(rx*rz);      R[t][7]= s*rx+oc*(ry*rz);      R[t][8]=1.f+oc*(-ry*ry-rx*rx);
    }
    if(t<NS) sh[t]=shapes[b*NS+t];
    __syncthreads();

    // pose_feature (padded to PSTR, pad = 0)
    for(int idx=t; idx<PSTR; idx+=64){
        float v = 0.f;
        if(idx<NP){
            int j = 1 + idx/9, e = idx%9;
            v = R[j][e] - ((e==0||e==4||e==8)?1.f:0.f);
        }
        ws[WS_PF + b*PSTR + idx] = v;
    }
    // Jrest = JT + JS @ shapes
    if(t<NJ){
        #pragma unroll
        for(int d=0;d<3;d++){
            float a = ws[WS_JS + t*33 + d];
            #pragma unroll
            for(int l=0;l<NS;l++) a = fmaf(sh[l], ws[WS_JS + t*33 + 3 + d*10 + l], a);
            jrest[t][d]=a;
        }
    }
    __syncthreads();
    if(t<NJ){
        int p = c_par[t];
        #pragma unroll
        for(int d=0;d<3;d++) rel[t][d] = (t==0) ? jrest[0][d] : jrest[t][d]-jrest[p][d];
    }
    __syncthreads();
    if(t<9) chR[0][t]=R[0][t];
    if(t<3) chT[0][t]=rel[0][t];
    __syncthreads();
    for(int i=1;i<NJ;i++){
        if(t<12){
            int r=t>>2, cc=t&3, p=c_par[i];
            if(cc<3){
                chR[i][r*3+cc] = chR[p][r*3+0]*R[i][0*3+cc] + chR[p][r*3+1]*R[i][1*3+cc] + chR[p][r*3+2]*R[i][2*3+cc];
            } else {
                chT[i][r] = chR[p][r*3+0]*rel[i][0] + chR[p][r*3+1]*rel[i][1] + chR[p][r*3+2]*rel[i][2] + chT[p][r];
            }
        }
        __syncthreads();
    }
    // A (trans corrected) then G = rotg @ A, store 3x4 row-major
    if(t<NJ){
        float rg[9];
        #pragma unroll
        for(int k=0;k<9;k++) rg[k]=R[24][k];
        float at[3];
        #pragma unroll
        for(int r=0;r<3;r++){
            float tj = chR[t][r*3+0]*jrest[t][0] + chR[t][r*3+1]*jrest[t][1] + chR[t][r*3+2]*jrest[t][2];
            at[r] = chT[t][r] - tj;
        }
        float* g = &ws[WS_G + b*288 + t*12];
        #pragma unroll
        for(int r=0;r<3;r++){
            #pragma unroll
            for(int cc=0;cc<3;cc++)
                g[r*4+cc] = rg[r*3+0]*chR[t][0*3+cc] + rg[r*3+1]*chR[t][1*3+cc] + rg[r*3+2]*chR[t][2*3+cc];
            g[r*4+3] = rg[r*3+0]*at[0] + rg[r*3+1]*at[1] + rg[r*3+2]*at[2];
        }
    }
}

// ---------------- K3: fused v_shaped + pose offsets + LBS ----------------
__global__ __launch_bounds__(256) void k_main(const float* __restrict__ vt,
                                              const float* __restrict__ sd,
                                              const float* __restrict__ pd,
                                              const float* __restrict__ wts,
                                              const float* __restrict__ th,
                                              const float* __restrict__ shapes,
                                              const float* __restrict__ ws,
                                              float* __restrict__ out){
    __shared__ __align__(16) float pf_s[BB*PSTR];
    __shared__ __align__(16) float g_s[BB*288];
    __shared__ float th_s[BB*3];
    __shared__ float sh_s[BB*NS];
    int tid = threadIdx.x;
    int b0  = blockIdx.y * BB;
    int v   = blockIdx.x * TV + tid;

    for(int i=tid; i<BB*PSTR; i+=TV) pf_s[i] = ws[WS_PF + b0*PSTR + i];
    for(int i=tid; i<BB*288;  i+=TV) g_s[i]  = ws[WS_G  + b0*288  + i];
    if(tid<BB*3)  th_s[tid] = th[b0*3+tid];
    if(tid<BB*NS) sh_s[tid] = shapes[b0*NS+tid];
    __syncthreads();
    if(v>=NV) return;

    // v_shaped = v_template + shapedirs @ shapes
    float sdv[30];
    {
        const float2* sp = (const float2*)(sd + (size_t)v*30);
        #pragma unroll
        for(int i=0;i<15;i++){ float2 s2 = sp[i]; sdv[2*i]=s2.x; sdv[2*i+1]=s2.y; }
    }
    float vt0=vt[v*3], vt1=vt[v*3+1], vt2=vt[v*3+2];
    float vp[BB][3];
    #pragma unroll
    for(int b=0;b<BB;b++){
        #pragma unroll
        for(int d=0;d<3;d++){
            float a = (d==0)?vt0:((d==1)?vt1:vt2);
            #pragma unroll
            for(int l=0;l<NS;l++) a = fmaf(sh_s[b*NS+l], sdv[d*10+l], a);
            vp[b][d]=a;
        }
    }
    // + pose_feature @ posedirs
    const float* pcol = pd + (size_t)v*3;
    int p=0;
    for(; p<=NP-4; p+=4){
        float pdv[4][3];
        #pragma unroll
        for(int q=0;q<4;q++){
            size_t base = (size_t)(p+q)*(NV*3);
            pdv[q][0]=pcol[base]; pdv[q][1]=pcol[base+1]; pdv[q][2]=pcol[base+2];
        }
        #pragma unroll
        for(int b=0;b<BB;b++){
            float4 f = *(const float4*)&pf_s[b*PSTR+p];
            #pragma unroll
            for(int d=0;d<3;d++)
                vp[b][d] = fmaf(f.x,pdv[0][d], fmaf(f.y,pdv[1][d], fmaf(f.z,pdv[2][d], fmaf(f.w,pdv[3][d], vp[b][d]))));
        }
    }
    for(; p<NP; p++){
        size_t base=(size_t)p*(NV*3);
        float p0=pcol[base], p1=pcol[base+1], p2=pcol[base+2];
        #pragma unroll
        for(int b=0;b<BB;b++){
            float f = pf_s[b*PSTR+p];
            vp[b][0]=fmaf(f,p0,vp[b][0]); vp[b][1]=fmaf(f,p1,vp[b][1]); vp[b][2]=fmaf(f,p2,vp[b][2]);
        }
    }
    // LBS blend + global transform (rot folded into G)
    float w[24];
    {
        const float4* wp = (const float4*)(wts + (size_t)v*24);
        #pragma unroll
        for(int i=0;i<6;i++){
            float4 u = wp[i];
            w[i*4+0]=u.x; w[i*4+1]=u.y; w[i*4+2]=u.z; w[i*4+3]=u.w;
        }
    }
    #pragma unroll 1
    for(int b=0;b<BB;b++){
        float4 T0=make_float4(0.f,0.f,0.f,0.f), T1=T0, T2=T0;
        #pragma unroll
        for(int j=0;j<NJ;j++){
            float wj = w[j];
            const float4* g = (const float4*)&g_s[b*288 + j*12];
            float4 g0=g[0], g1=g[1], g2=g[2];
            T0.x=fmaf(wj,g0.x,T0.x); T0.y=fmaf(wj,g0.y,T0.y); T0.z=fmaf(wj,g0.z,T0.z); T0.w=fmaf(wj,g0.w,T0.w);
            T1.x=fmaf(wj,g1.x,T1.x); T1.y=fmaf(wj,g1.y,T1.y); T1.z=fmaf(wj,g1.z,T1.z); T1.w=fmaf(wj,g1.w,T1.w);
            T2.x=fmaf(wj,g2.x,T2.x); T2.y=fmaf(wj,g2.y,T2.y); T2.z=fmaf(wj,g2.z,T2.z); T2.w=fmaf(wj,g2.w,T2.w);
        }
        float x=vp[b][0], y=vp[b][1], z=vp[b][2];
        float ox = fmaf(T0.x,x, fmaf(T0.y,y, fmaf(T0.z,z, T0.w))) + th_s[b*3+0];
        float oy = fmaf(T1.x,x, fmaf(T1.y,y, fmaf(T1.z,z, T1.w))) + th_s[b*3+1];
        float oz = fmaf(T2.x,x, fmaf(T2.y,y, fmaf(T2.z,z, T2.w))) + th_s[b*3+2];
        size_t o = ((size_t)(b0+b)*NV + v)*3;
        out[o]=ox; out[o+1]=oy; out[o+2]=oz;
    }
}

extern "C" void kernel_launch(void* const* d_in, const int* in_sizes, int n_in,
                              void* d_out, int out_size, void* d_ws, size_t ws_size,
                              hipStream_t stream){
    const float* poses  = (const float*)d_in[0];
    const float* shapes = (const float*)d_in[1];
    const float* Rh     = (const float*)d_in[2];
    const float* Th     = (const float*)d_in[3];
    const float* vt     = (const float*)d_in[4];
    const float* sd     = (const float*)d_in[5];
    const float* pdirs  = (const float*)d_in[6];
    const float* jreg   = (const float*)d_in[7];
    const float* wts    = (const float*)d_in[8];
    float* ws = (float*)d_ws;   // needs ~1.02 MB
    float* out = (float*)d_out;

    hipLaunchKernelGGL(k_jreg,  dim3(NJ), dim3(256), 0, stream, jreg, vt, sd, ws);
    hipLaunchKernelGGL(k_chain, dim3(BN), dim3(64),  0, stream, poses, shapes, Rh, ws);
    hipLaunchKernelGGL(k_main,  dim3((NV+TV-1)/TV, BN/BB), dim3(256), 0, stream,
                       vt, sd, pdirs, wts, Th, shapes, ws, out);
}

// Round 3
// 200.704 us; speedup vs baseline: 1.5576x; 1.5576x over previous
//
#include <hip/hip_runtime.h>

// SMPL forward, all I/O fp32. B=512, V=6890, J=24, NS=10, NP=207.
//
// Full path (ws_size >= ~10.6MB):
//  k_jreg : partial J_regressor folds (24x8 blocks) -> ws partials
//  k_conv : posedirs fp32 [207,20670] -> bf16 BT [20736,224] (transposed, zero-padded)
//  k_chain: Rodrigues + chain + G = rot*A; pose_feature -> fp32 PF + bf16 A [512,224]
//  k_gemm : MFMA bf16: offset[512,20670] = A @ BT^T  -> written into d_out (scratch)
//  k_lbs  : in-place: out = LBS(v_template + sd@sh + offset) + Th
// Fallback (small ws): round-2 fused k_main.

#define BN 512
#define NV 6890
#define NJ 24
#define NS 10
#define NP 207
#define PSTR 208
#define KP 224          // padded K for MFMA (7 x 32)
#define NPAD 20736      // padded N (81 x 256)
#define BB 8
#define TV 256

// unified ws layout (float offsets)
#define WS_JSP 0                      // 24*8*33 = 6336
#define WS_G   6400                   // 512*288 = 147456 -> ends 153856
#define WS_PF  153856                 // 512*208 = 106496 -> ends 260352 (fallback only)
// u16 offsets
#define WS_A16 520704                 // 512*224 u16 = 114688 -> ends 635392
#define WS_BT16 635392                // 20736*224 u16 = 4644864 -> ends 5280256
#define FULL_NEED ((size_t)10560512)

typedef unsigned short u16;
typedef short bf16x8 __attribute__((ext_vector_type(8)));
typedef float f32x4  __attribute__((ext_vector_type(4)));

__constant__ int c_par[NJ] = {-1,0,0,0,1,2,3,4,5,6,7,8,9,9,9,12,13,14,16,17,18,19,20,21};

__device__ __forceinline__ u16 f2bf(float f){
    union { float f; unsigned i; } x; x.f = f;
    unsigned r = x.i + 0x7fffu + ((x.i >> 16) & 1u);   // RNE
    return (u16)(r >> 16);
}

// ---------------- k_jreg: partial folds of J_regressor ----------------
__global__ __launch_bounds__(256) void k_jreg(const float* __restrict__ jreg,
                                              const float* __restrict__ vt,
                                              const float* __restrict__ sd,
                                              float* __restrict__ ws){
    int j = blockIdx.x, s = blockIdx.y;
    int tid = threadIdx.x;
    int v0 = s*864, v1 = min(NV, v0+864);
    float acc[33];
    #pragma unroll
    for(int k=0;k<33;k++) acc[k]=0.f;
    for(int v=v0+tid; v<v1; v+=256){
        float jr = jreg[j*NV+v];
        #pragma unroll
        for(int d=0;d<3;d++) acc[d] = fmaf(jr, vt[v*3+d], acc[d]);
        const float2* sp = (const float2*)(sd + (size_t)v*30);
        #pragma unroll
        for(int k=0;k<15;k++){
            float2 s2 = sp[k];
            acc[3+2*k]   = fmaf(jr, s2.x, acc[3+2*k]);
            acc[3+2*k+1] = fmaf(jr, s2.y, acc[3+2*k+1]);
        }
    }
    __shared__ float red[4][33];
    int lane = tid & 63, wv = tid >> 6;
    #pragma unroll
    for(int k=0;k<33;k++){
        float val = acc[k];
        #pragma unroll
        for(int off=32; off; off>>=1) val += __shfl_down(val, off, 64);
        if(lane==0) red[wv][k]=val;
    }
    __syncthreads();
    if(tid<33) ws[WS_JSP + (j*8+s)*33 + tid] = red[0][tid]+red[1][tid]+red[2][tid]+red[3][tid];
}

// ---------------- k_conv: posedirs -> bf16 BT[n][k], transposed+padded ----------------
__global__ __launch_bounds__(256) void k_conv(const float* __restrict__ pd,
                                              u16* __restrict__ bt){
    __shared__ u16 tile[32][65];
    int t = threadIdx.x;
    int n0 = blockIdx.x * 64;
    int k0 = blockIdx.y * 32;
    int nl = t & 63, kb = (t>>6)*8;
    int n = n0 + nl;
    #pragma unroll
    for(int i=0;i<8;i++){
        int k = k0 + kb + i;
        float v = (k<NP && n<NV*3) ? pd[(size_t)k*(NV*3) + n] : 0.f;
        tile[kb+i][nl] = f2bf(v);
    }
    __syncthreads();
    int nl2 = t >> 2, kc = t & 3;
    union { u16 s[8]; uint4 q; } u;
    #pragma unroll
    for(int i=0;i<8;i++) u.s[i] = tile[kc*8+i][nl2];
    u16* dst = bt + (size_t)(n0 + nl2)*KP + k0 + kc*8;
    *(uint4*)dst = u.q;
}

// ---------------- k_chain: rodrigues + chain + G + pose feature ----------------
__global__ __launch_bounds__(64) void k_chain(const float* __restrict__ poses,
                                              const float* __restrict__ shapes,
                                              const float* __restrict__ Rh,
                                              float* __restrict__ ws,
                                              u16* __restrict__ aout){
    int b = blockIdx.x;
    int t = threadIdx.x;
    __shared__ float R[25][9];
    __shared__ float sh[NS];
    __shared__ float js[792];
    __shared__ float jrest[NJ][3];
    __shared__ float rel[NJ][3];
    __shared__ float chR[NJ][9];
    __shared__ float chT[NJ][3];

    if(t<25){
        float x,y,z;
        if(t<24){ x=poses[b*72+t*3]; y=poses[b*72+t*3+1]; z=poses[b*72+t*3+2]; }
        else    { x=Rh[b*3];         y=Rh[b*3+1];         z=Rh[b*3+2]; }
        float ax=x+1e-8f, ay=y+1e-8f, az=z+1e-8f;
        float ang = sqrtf(ax*ax+ay*ay+az*az);
        float inv = 1.f/ang;
        float rx=x*inv, ry=y*inv, rz=z*inv;
        float s = sinf(ang), c = cosf(ang), oc = 1.f - c;
        R[t][0]=1.f+oc*(-rz*rz-ry*ry); R[t][1]=-s*rz+oc*(rx*ry);      R[t][2]= s*ry+oc*(rx*rz);
        R[t][3]= s*rz+oc*(rx*ry);      R[t][4]=1.f+oc*(-rz*rz-rx*rx); R[t][5]=-s*rx+oc*(ry*rz);
        R[t][6]=-s*ry+oc*(rx*rz);      R[t][7]= s*rx+oc*(ry*rz);      R[t][8]=1.f+oc*(-ry*ry-rx*rx);
    }
    if(t<NS) sh[t]=shapes[b*NS+t];
    // reduce J_regressor partials
    for(int idx=t; idx<792; idx+=64){
        int j = idx/33, e = idx%33;
        float a = 0.f;
        #pragma unroll
        for(int s=0;s<8;s++) a += ws[WS_JSP + (j*8+s)*33 + e];
        js[idx]=a;
    }
    __syncthreads();

    // pose feature: fp32 (fallback) + bf16 A (full path)
    for(int idx=t; idx<KP; idx+=64){
        float v = 0.f;
        if(idx<NP){
            int j = 1 + idx/9, e = idx%9;
            v = R[j][e] - ((e==0||e==4||e==8)?1.f:0.f);
        }
        if(idx<PSTR) ws[WS_PF + b*PSTR + idx] = v;
        if(aout) aout[b*KP + idx] = f2bf(v);
    }
    if(t<NJ){
        #pragma unroll
        for(int d=0;d<3;d++){
            float a = js[t*33 + d];
            #pragma unroll
            for(int l=0;l<NS;l++) a = fmaf(sh[l], js[t*33 + 3 + d*10 + l], a);
            jrest[t][d]=a;
        }
    }
    __syncthreads();
    if(t<NJ){
        int p = c_par[t];
        #pragma unroll
        for(int d=0;d<3;d++) rel[t][d] = (t==0) ? jrest[0][d] : jrest[t][d]-jrest[p][d];
    }
    __syncthreads();
    if(t<9) chR[0][t]=R[0][t];
    if(t<3) chT[0][t]=rel[0][t];
    __syncthreads();
    for(int i=1;i<NJ;i++){
        if(t<12){
            int r=t>>2, cc=t&3, p=c_par[i];
            if(cc<3){
                chR[i][r*3+cc] = chR[p][r*3+0]*R[i][0*3+cc] + chR[p][r*3+1]*R[i][1*3+cc] + chR[p][r*3+2]*R[i][2*3+cc];
            } else {
                chT[i][r] = chR[p][r*3+0]*rel[i][0] + chR[p][r*3+1]*rel[i][1] + chR[p][r*3+2]*rel[i][2] + chT[p][r];
            }
        }
        __syncthreads();
    }
    if(t<NJ){
        float rg[9];
        #pragma unroll
        for(int k=0;k<9;k++) rg[k]=R[24][k];
        float at[3];
        #pragma unroll
        for(int r=0;r<3;r++){
            float tj = chR[t][r*3+0]*jrest[t][0] + chR[t][r*3+1]*jrest[t][1] + chR[t][r*3+2]*jrest[t][2];
            at[r] = chT[t][r] - tj;
        }
        float* g = &ws[WS_G + b*288 + t*12];
        #pragma unroll
        for(int r=0;r<3;r++){
            #pragma unroll
            for(int cc=0;cc<3;cc++)
                g[r*4+cc] = rg[r*3+0]*chR[t][0*3+cc] + rg[r*3+1]*chR[t][1*3+cc] + rg[r*3+2]*chR[t][2*3+cc];
            g[r*4+3] = rg[r*3+0]*at[0] + rg[r*3+1]*at[1] + rg[r*3+2]*at[2];
        }
    }
}

// ---------------- k_gemm: offset = pf @ posedirs via MFMA bf16 ----------------
// A [512,224] bf16 row-major; BT [20736,224] bf16 (B transposed). C -> out fp32 [512,20670].
__global__ __launch_bounds__(256) void k_gemm(const u16* __restrict__ A,
                                              const u16* __restrict__ BT,
                                              float* __restrict__ out){
    int t = threadIdx.x;
    int wave = t>>6, lane = t&63;
    int quad = lane>>4, l16 = lane&15;
    int m0 = blockIdx.x * 32;
    int n0 = blockIdx.y * 256 + wave*64;
    f32x4 zz = {0.f,0.f,0.f,0.f};
    f32x4 acc[2][4];
    #pragma unroll
    for(int mi=0;mi<2;mi++)
        #pragma unroll
        for(int s=0;s<4;s++) acc[mi][s]=zz;
    const u16* a0 = A + (size_t)(m0 + l16)*KP + quad*8;
    const u16* a1 = a0 + 16*KP;
    const u16* bp0 = BT + (size_t)(n0 + 0*16 + l16)*KP + quad*8;
    const u16* bp1 = BT + (size_t)(n0 + 1*16 + l16)*KP + quad*8;
    const u16* bp2 = BT + (size_t)(n0 + 2*16 + l16)*KP + quad*8;
    const u16* bp3 = BT + (size_t)(n0 + 3*16 + l16)*KP + quad*8;
    #pragma unroll
    for(int k0=0;k0<KP;k0+=32){
        bf16x8 af0 = *(const bf16x8*)(a0 + k0);
        bf16x8 af1 = *(const bf16x8*)(a1 + k0);
        bf16x8 b0 = *(const bf16x8*)(bp0 + k0);
        bf16x8 b1 = *(const bf16x8*)(bp1 + k0);
        bf16x8 b2 = *(const bf16x8*)(bp2 + k0);
        bf16x8 b3 = *(const bf16x8*)(bp3 + k0);
        acc[0][0] = __builtin_amdgcn_mfma_f32_16x16x32_bf16(af0, b0, acc[0][0], 0,0,0);
        acc[1][0] = __builtin_amdgcn_mfma_f32_16x16x32_bf16(af1, b0, acc[1][0], 0,0,0);
        acc[0][1] = __builtin_amdgcn_mfma_f32_16x16x32_bf16(af0, b1, acc[0][1], 0,0,0);
        acc[1][1] = __builtin_amdgcn_mfma_f32_16x16x32_bf16(af1, b1, acc[1][1], 0,0,0);
        acc[0][2] = __builtin_amdgcn_mfma_f32_16x16x32_bf16(af0, b2, acc[0][2], 0,0,0);
        acc[1][2] = __builtin_amdgcn_mfma_f32_16x16x32_bf16(af1, b2, acc[1][2], 0,0,0);
        acc[0][3] = __builtin_amdgcn_mfma_f32_16x16x32_bf16(af0, b3, acc[0][3], 0,0,0);
        acc[1][3] = __builtin_amdgcn_mfma_f32_16x16x32_bf16(af1, b3, acc[1][3], 0,0,0);
    }
    // C/D layout: col(N)=lane&15, row(M)=quad*4+reg
    #pragma unroll
    for(int mi=0;mi<2;mi++){
        int mb = m0 + mi*16 + quad*4;
        #pragma unroll
        for(int s=0;s<4;s++){
            int n = n0 + s*16 + l16;
            if(n < NV*3){
                #pragma unroll
                for(int r=0;r<4;r++) out[(size_t)(mb+r)*(NV*3) + n] = acc[mi][s][r];
            }
        }
    }
}

// ---------------- k_lbs: in-place v_shaped + offset + LBS + Th ----------------
__global__ __launch_bounds__(256) void k_lbs(const float* __restrict__ vt,
                                             const float* __restrict__ sd,
                                             const float* __restrict__ wts,
                                             const float* __restrict__ th,
                                             const float* __restrict__ shapes,
                                             const float* __restrict__ ws,
                                             float* __restrict__ out){
    int tid = threadIdx.x;
    int b0  = blockIdx.y * BB;
    int v   = blockIdx.x * TV + tid;
    if(v>=NV) return;

    float sdv[30];
    {
        const float2* sp = (const float2*)(sd + (size_t)v*30);
        #pragma unroll
        for(int i=0;i<15;i++){ float2 s2 = sp[i]; sdv[2*i]=s2.x; sdv[2*i+1]=s2.y; }
    }
    float vt0=vt[v*3], vt1=vt[v*3+1], vt2=vt[v*3+2];
    float w[24];
    {
        const float4* wp = (const float4*)(wts + (size_t)v*24);
        #pragma unroll
        for(int i=0;i<6;i++){
            float4 u = wp[i];
            w[i*4+0]=u.x; w[i*4+1]=u.y; w[i*4+2]=u.z; w[i*4+3]=u.w;
        }
    }
    #pragma unroll 1
    for(int b=0;b<BB;b++){
        int bb = b0 + b;
        const float* gb  = ws + WS_G + (size_t)bb*288;   // uniform -> scalar loads
        const float* shb = shapes + bb*NS;               // uniform
        float* op = out + (size_t)bb*(NV*3) + v*3;
        float o0 = op[0], o1 = op[1], o2 = op[2];
        float vs[3];
        #pragma unroll
        for(int d=0;d<3;d++){
            float a = (d==0)?(vt0+o0):((d==1)?(vt1+o1):(vt2+o2));
            #pragma unroll
            for(int l=0;l<NS;l++) a = fmaf(shb[l], sdv[d*10+l], a);
            vs[d]=a;
        }
        float T[12];
        #pragma unroll
        for(int e=0;e<12;e++) T[e]=0.f;
        #pragma unroll
        for(int j=0;j<NJ;j++){
            float wj = w[j];
            #pragma unroll
            for(int e=0;e<12;e++) T[e] = fmaf(wj, gb[j*12+e], T[e]);
        }
        float x=vs[0], y=vs[1], z=vs[2];
        float ox = fmaf(T[0],x, fmaf(T[1],y, fmaf(T[2], z, T[3])))  + th[bb*3+0];
        float oy = fmaf(T[4],x, fmaf(T[5],y, fmaf(T[6], z, T[7])))  + th[bb*3+1];
        float oz = fmaf(T[8],x, fmaf(T[9],y, fmaf(T[10],z, T[11]))) + th[bb*3+2];
        op[0]=ox; op[1]=oy; op[2]=oz;
    }
}

// ---------------- fallback: round-2 fused k_main ----------------
__global__ __launch_bounds__(256) void k_main(const float* __restrict__ vt,
                                              const float* __restrict__ sd,
                                              const float* __restrict__ pd,
                                              const float* __restrict__ wts,
                                              const float* __restrict__ th,
                                              const float* __restrict__ shapes,
                                              const float* __restrict__ ws,
                                              float* __restrict__ out){
    __shared__ __align__(16) float pf_s[BB*PSTR];
    __shared__ __align__(16) float g_s[BB*288];
    __shared__ float th_s[BB*3];
    __shared__ float sh_s[BB*NS];
    int tid = threadIdx.x;
    int b0  = blockIdx.y * BB;
    int v   = blockIdx.x * TV + tid;

    for(int i=tid; i<BB*PSTR; i+=TV) pf_s[i] = ws[WS_PF + b0*PSTR + i];
    for(int i=tid; i<BB*288;  i+=TV) g_s[i]  = ws[WS_G  + b0*288  + i];
    if(tid<BB*3)  th_s[tid] = th[b0*3+tid];
    if(tid<BB*NS) sh_s[tid] = shapes[b0*NS+tid];
    __syncthreads();
    if(v>=NV) return;

    float sdv[30];
    {
        const float2* sp = (const float2*)(sd + (size_t)v*30);
        #pragma unroll
        for(int i=0;i<15;i++){ float2 s2 = sp[i]; sdv[2*i]=s2.x; sdv[2*i+1]=s2.y; }
    }
    float vt0=vt[v*3], vt1=vt[v*3+1], vt2=vt[v*3+2];
    float vp[BB][3];
    #pragma unroll
    for(int b=0;b<BB;b++){
        #pragma unroll
        for(int d=0;d<3;d++){
            float a = (d==0)?vt0:((d==1)?vt1:vt2);
            #pragma unroll
            for(int l=0;l<NS;l++) a = fmaf(sh_s[b*NS+l], sdv[d*10+l], a);
            vp[b][d]=a;
        }
    }
    const float* pcol = pd + (size_t)v*3;
    int p=0;
    for(; p<=NP-4; p+=4){
        float pdv[4][3];
        #pragma unroll
        for(int q=0;q<4;q++){
            size_t base = (size_t)(p+q)*(NV*3);
            pdv[q][0]=pcol[base]; pdv[q][1]=pcol[base+1]; pdv[q][2]=pcol[base+2];
        }
        #pragma unroll
        for(int b=0;b<BB;b++){
            float4 f = *(const float4*)&pf_s[b*PSTR+p];
            #pragma unroll
            for(int d=0;d<3;d++)
                vp[b][d] = fmaf(f.x,pdv[0][d], fmaf(f.y,pdv[1][d], fmaf(f.z,pdv[2][d], fmaf(f.w,pdv[3][d], vp[b][d]))));
        }
    }
    for(; p<NP; p++){
        size_t base=(size_t)p*(NV*3);
        float p0=pcol[base], p1=pcol[base+1], p2=pcol[base+2];
        #pragma unroll
        for(int b=0;b<BB;b++){
            float f = pf_s[b*PSTR+p];
            vp[b][0]=fmaf(f,p0,vp[b][0]); vp[b][1]=fmaf(f,p1,vp[b][1]); vp[b][2]=fmaf(f,p2,vp[b][2]);
        }
    }
    float w[24];
    {
        const float4* wp = (const float4*)(wts + (size_t)v*24);
        #pragma unroll
        for(int i=0;i<6;i++){
            float4 u = wp[i];
            w[i*4+0]=u.x; w[i*4+1]=u.y; w[i*4+2]=u.z; w[i*4+3]=u.w;
        }
    }
    #pragma unroll 1
    for(int b=0;b<BB;b++){
        float4 T0=make_float4(0.f,0.f,0.f,0.f), T1=T0, T2=T0;
        #pragma unroll
        for(int j=0;j<NJ;j++){
            float wj = w[j];
            const float4* g = (const float4*)&g_s[b*288 + j*12];
            float4 g0=g[0], g1=g[1], g2=g[2];
            T0.x=fmaf(wj,g0.x,T0.x); T0.y=fmaf(wj,g0.y,T0.y); T0.z=fmaf(wj,g0.z,T0.z); T0.w=fmaf(wj,g0.w,T0.w);
            T1.x=fmaf(wj,g1.x,T1.x); T1.y=fmaf(wj,g1.y,T1.y); T1.z=fmaf(wj,g1.z,T1.z); T1.w=fmaf(wj,g1.w,T1.w);
            T2.x=fmaf(wj,g2.x,T2.x); T2.y=fmaf(wj,g2.y,T2.y); T2.z=fmaf(wj,g2.z,T2.z); T2.w=fmaf(wj,g2.w,T2.w);
        }
        float x=vp[b][0], y=vp[b][1], z=vp[b][2];
        float ox = fmaf(T0.x,x, fmaf(T0.y,y, fmaf(T0.z,z, T0.w))) + th_s[b*3+0];
        float oy = fmaf(T1.x,x, fmaf(T1.y,y, fmaf(T1.z,z, T1.w))) + th_s[b*3+1];
        float oz = fmaf(T2.x,x, fmaf(T2.y,y, fmaf(T2.z,z, T2.w))) + th_s[b*3+2];
        size_t o = ((size_t)(b0+b)*NV + v)*3;
        out[o]=ox; out[o+1]=oy; out[o+2]=oz;
    }
}

extern "C" void kernel_launch(void* const* d_in, const int* in_sizes, int n_in,
                              void* d_out, int out_size, void* d_ws, size_t ws_size,
                              hipStream_t stream){
    const float* poses  = (const float*)d_in[0];
    const float* shapes = (const float*)d_in[1];
    const float* Rh     = (const float*)d_in[2];
    const float* Th     = (const float*)d_in[3];
    const float* vt     = (const float*)d_in[4];
    const float* sd     = (const float*)d_in[5];
    const float* pdirs  = (const float*)d_in[6];
    const float* jreg   = (const float*)d_in[7];
    const float* wts    = (const float*)d_in[8];
    float* ws  = (float*)d_ws;
    float* out = (float*)d_out;
    bool full = (ws_size >= FULL_NEED);

    hipLaunchKernelGGL(k_jreg, dim3(NJ,8), dim3(256), 0, stream, jreg, vt, sd, ws);
    hipLaunchKernelGGL(k_chain, dim3(BN), dim3(64), 0, stream, poses, shapes, Rh, ws,
                       full ? ((u16*)d_ws + WS_A16) : (u16*)nullptr);
    if(full){
        hipLaunchKernelGGL(k_conv, dim3(NPAD/64, KP/32), dim3(256), 0, stream,
                           pdirs, (u16*)d_ws + WS_BT16);
        hipLaunchKernelGGL(k_gemm, dim3(BN/32, NPAD/256), dim3(256), 0, stream,
                           (u16*)d_ws + WS_A16, (u16*)d_ws + WS_BT16, out);
        hipLaunchKernelGGL(k_lbs, dim3((NV+TV-1)/TV, BN/BB), dim3(256), 0, stream,
                           vt, sd, wts, Th, shapes, ws, out);
    } else {
        hipLaunchKernelGGL(k_main, dim3((NV+TV-1)/TV, BN/BB), dim3(256), 0, stream,
                           vt, sd, pdirs, wts, Th, shapes, ws, out);
    }
}

// Round 4
// 164.117 us; speedup vs baseline: 1.9048x; 1.2229x over previous
//
#include <hip/hip_runtime.h>

// SMPL forward, all I/O fp32. B=512, V=6890, J=24, NS=10, NP=207.
//
// Full path (ws >= 10.38MB):
//  k_jreg : partial J_regressor folds (24x8 blocks) -> ws partials
//  k_conv : BT[d][v][k] bf16: k<207 posedirs[k][v*3+d]; 207..216 shapedirs[v][d][k-207]; pad 0
//  k_wconv: wTT[v][32] bf16 = weights[v][j] (j<24), pad 0
//  k_chain: Rodrigues + chain + G=rot*A; emits A1[b][224]=bf16[pf|shapes], A2[e][b][32]=bf16 G
//  k_fused: MFMA GEMM1 (vposed-vt) + MFMA GEMM2 (T blend) + fp32 epilogue -> out
// Fallback (small ws): round-2 fused k_main.

#define BN 512
#define NV 6890
#define NVP 6912        // padded V (216 x 32)
#define NJ 24
#define NS 10
#define NP 207
#define PSTR 208
#define KP 224          // padded K for GEMM1 (207 pf + 10 shapes + 7 pad)
#define K2 32           // padded K for GEMM2 (24 joints + 8 pad)
#define NPAD 20736      // 3*NVP
#define BB 8
#define TV 256

// fallback ws layout (float offsets)
#define WS_JSP 0                      // 24*8*33 = 6336
#define WS_G   6400                   // 512*288
#define WS_PF  153856                 // 512*208 -> ends 260352 floats
// full-path u16 offsets (after JSP: 6400 floats = 12800 u16)
#define WS_A1  12800                  // 512*224 = 114688 -> 127488
#define WS_A2  127488                 // 12*512*32 = 196608 -> 324096
#define WS_WT  324096                 // 6912*32 = 221184 -> 545280
#define WS_BT  545280                 // 3*6912*224 = 4644864 -> 5190144 u16
#define FULL_NEED ((size_t)10380288)
#define FB_NEED   ((size_t)1041408)

typedef unsigned short u16;
typedef short bf16x8 __attribute__((ext_vector_type(8)));
typedef float f32x4  __attribute__((ext_vector_type(4)));

__constant__ int c_par[NJ] = {-1,0,0,0,1,2,3,4,5,6,7,8,9,9,9,12,13,14,16,17,18,19,20,21};

__device__ __forceinline__ u16 f2bf(float f){
    union { float f; unsigned i; } x; x.f = f;
    unsigned r = x.i + 0x7fffu + ((x.i >> 16) & 1u);   // RNE
    return (u16)(r >> 16);
}

// ---------------- k_jreg: partial folds of J_regressor ----------------
__global__ __launch_bounds__(256) void k_jreg(const float* __restrict__ jreg,
                                              const float* __restrict__ vt,
                                              const float* __restrict__ sd,
                                              float* __restrict__ ws){
    int j = blockIdx.x, s = blockIdx.y;
    int tid = threadIdx.x;
    int v0 = s*864, v1 = min(NV, v0+864);
    float acc[33];
    #pragma unroll
    for(int k=0;k<33;k++) acc[k]=0.f;
    for(int v=v0+tid; v<v1; v+=256){
        float jr = jreg[j*NV+v];
        #pragma unroll
        for(int d=0;d<3;d++) acc[d] = fmaf(jr, vt[v*3+d], acc[d]);
        const float2* sp = (const float2*)(sd + (size_t)v*30);
        #pragma unroll
        for(int k=0;k<15;k++){
            float2 s2 = sp[k];
            acc[3+2*k]   = fmaf(jr, s2.x, acc[3+2*k]);
            acc[3+2*k+1] = fmaf(jr, s2.y, acc[3+2*k+1]);
        }
    }
    __shared__ float red[4][33];
    int lane = tid & 63, wv = tid >> 6;
    #pragma unroll
    for(int k=0;k<33;k++){
        float val = acc[k];
        #pragma unroll
        for(int off=32; off; off>>=1) val += __shfl_down(val, off, 64);
        if(lane==0) red[wv][k]=val;
    }
    __syncthreads();
    if(tid<33) ws[WS_JSP + (j*8+s)*33 + tid] = red[0][tid]+red[1][tid]+red[2][tid]+red[3][tid];
}

// ---------------- k_conv: build BT[d][v][k] bf16 ----------------
__global__ __launch_bounds__(256) void k_conv(const float* __restrict__ pd,
                                              const float* __restrict__ sd,
                                              u16* __restrict__ bt){
    __shared__ u16 tile[32][65];
    int t = threadIdx.x;
    int n0 = blockIdx.x * 64;
    int k0 = blockIdx.y * 32;
    int nl = t & 63, kb = (t>>6)*8;
    int n = n0 + nl;
    #pragma unroll
    for(int i=0;i<8;i++){
        int k = k0 + kb + i;
        float v = 0.f;
        if(n < NV*3){
            if(k < NP)           v = pd[(size_t)k*(NV*3) + n];
            else if(k < NP+NS)   v = sd[(size_t)(n/3)*30 + (n%3)*10 + (k-NP)];
        }
        tile[kb+i][nl] = f2bf(v);
    }
    __syncthreads();
    int nl2 = t >> 2, kc = t & 3;
    union { u16 s[8]; uint4 q; } u;
    #pragma unroll
    for(int i=0;i<8;i++) u.s[i] = tile[kc*8+i][nl2];
    int ng = n0 + nl2;
    int row = (ng%3)*NVP + ng/3;
    u16* dst = bt + (size_t)row*KP + k0 + kc*8;
    *(uint4*)dst = u.q;
}

// ---------------- k_wconv: weights -> wTT[v][32] bf16 ----------------
__global__ __launch_bounds__(256) void k_wconv(const float* __restrict__ wts,
                                               u16* __restrict__ wt){
    int v = blockIdx.x*256 + threadIdx.x;
    if(v >= NVP) return;
    union { u16 s[32]; uint4 q[4]; } u;
    #pragma unroll
    for(int j=0;j<24;j++) u.s[j] = (v<NV) ? f2bf(wts[(size_t)v*24+j]) : (u16)0;
    #pragma unroll
    for(int j=24;j<32;j++) u.s[j]=0;
    uint4* dst = (uint4*)(wt + (size_t)v*K2);
    dst[0]=u.q[0]; dst[1]=u.q[1]; dst[2]=u.q[2]; dst[3]=u.q[3];
}

// ---------------- k_chain: rodrigues + chain + G + A1/A2 emit ----------------
__global__ __launch_bounds__(64) void k_chain(const float* __restrict__ poses,
                                              const float* __restrict__ shapes,
                                              const float* __restrict__ Rh,
                                              float* __restrict__ ws,
                                              u16* __restrict__ a1,
                                              u16* __restrict__ a2,
                                              int full){
    int b = blockIdx.x;
    int t = threadIdx.x;
    __shared__ float R[25][9];
    __shared__ float sh[NS];
    __shared__ float js[792];
    __shared__ float jrest[NJ][3];
    __shared__ float rel[NJ][3];
    __shared__ float chR[NJ][9];
    __shared__ float chT[NJ][3];
    __shared__ float Gs[NJ][12];

    if(t<25){
        float x,y,z;
        if(t<24){ x=poses[b*72+t*3]; y=poses[b*72+t*3+1]; z=poses[b*72+t*3+2]; }
        else    { x=Rh[b*3];         y=Rh[b*3+1];         z=Rh[b*3+2]; }
        float ax=x+1e-8f, ay=y+1e-8f, az=z+1e-8f;
        float ang = sqrtf(ax*ax+ay*ay+az*az);
        float inv = 1.f/ang;
        float rx=x*inv, ry=y*inv, rz=z*inv;
        float s = sinf(ang), c = cosf(ang), oc = 1.f - c;
        R[t][0]=1.f+oc*(-rz*rz-ry*ry); R[t][1]=-s*rz+oc*(rx*ry);      R[t][2]= s*ry+oc*(rx*rz);
        R[t][3]= s*rz+oc*(rx*ry);      R[t][4]=1.f+oc*(-rz*rz-rx*rx); R[t][5]=-s*rx+oc*(ry*rz);
        R[t][6]=-s*ry+oc*(rx*rz);      R[t][7]= s*rx+oc*(ry*rz);      R[t][8]=1.f+oc*(-ry*ry-rx*rx);
    }
    if(t<NS) sh[t]=shapes[b*NS+t];
    for(int idx=t; idx<792; idx+=64){
        int j = idx/33, e = idx%33;
        float a = 0.f;
        #pragma unroll
        for(int s=0;s<8;s++) a += ws[WS_JSP + (j*8+s)*33 + e];
        js[idx]=a;
    }
    __syncthreads();

    // pose feature -> A1 (full) or ws PF (fallback)
    for(int idx=t; idx<KP; idx+=64){
        float v = 0.f;
        if(idx<NP){
            int j = 1 + idx/9, e = idx%9;
            v = R[j][e] - ((e==0||e==4||e==8)?1.f:0.f);
        } else if(idx<NP+NS) v = sh[idx-NP];
        if(full){ a1[b*KP + idx] = f2bf(v); }
        else if(idx<PSTR) ws[WS_PF + b*PSTR + idx] = (idx<NP)?v:0.f;
    }
    if(t<NJ){
        #pragma unroll
        for(int d=0;d<3;d++){
            float a = js[t*33 + d];
            #pragma unroll
            for(int l=0;l<NS;l++) a = fmaf(sh[l], js[t*33 + 3 + d*10 + l], a);
            jrest[t][d]=a;
        }
    }
    __syncthreads();
    if(t<NJ){
        int p = c_par[t];
        #pragma unroll
        for(int d=0;d<3;d++) rel[t][d] = (t==0) ? jrest[0][d] : jrest[t][d]-jrest[p][d];
    }
    __syncthreads();
    if(t<9) chR[0][t]=R[0][t];
    if(t<3) chT[0][t]=rel[0][t];
    __syncthreads();
    for(int i=1;i<NJ;i++){
        if(t<12){
            int r=t>>2, cc=t&3, p=c_par[i];
            if(cc<3){
                chR[i][r*3+cc] = chR[p][r*3+0]*R[i][0*3+cc] + chR[p][r*3+1]*R[i][1*3+cc] + chR[p][r*3+2]*R[i][2*3+cc];
            } else {
                chT[i][r] = chR[p][r*3+0]*rel[i][0] + chR[p][r*3+1]*rel[i][1] + chR[p][r*3+2]*rel[i][2] + chT[p][r];
            }
        }
        __syncthreads();
    }
    if(t<NJ){
        float rg[9];
        #pragma unroll
        for(int k=0;k<9;k++) rg[k]=R[24][k];
        float at[3];
        #pragma unroll
        for(int r=0;r<3;r++){
            float tj = chR[t][r*3+0]*jrest[t][0] + chR[t][r*3+1]*jrest[t][1] + chR[t][r*3+2]*jrest[t][2];
            at[r] = chT[t][r] - tj;
        }
        #pragma unroll
        for(int r=0;r<3;r++){
            #pragma unroll
            for(int cc=0;cc<3;cc++)
                Gs[t][r*4+cc] = rg[r*3+0]*chR[t][0*3+cc] + rg[r*3+1]*chR[t][1*3+cc] + rg[r*3+2]*chR[t][2*3+cc];
            Gs[t][r*4+3] = rg[r*3+0]*at[0] + rg[r*3+1]*at[1] + rg[r*3+2]*at[2];
        }
    }
    __syncthreads();
    if(full){
        // A2[e][b][32] = bf16(G[b][j][e]) for j<24
        for(int idx=t; idx<12*K2; idx+=64){
            int e = idx/K2, k = idx%K2;
            float v = (k<NJ) ? Gs[k][e] : 0.f;
            a2[((size_t)e*BN + b)*K2 + k] = f2bf(v);
        }
    } else if(t<NJ){
        float* g = &ws[WS_G + b*288 + t*12];
        #pragma unroll
        for(int e=0;e<12;e++) g[e] = Gs[t][e];
    }
}

// ---------------- k_fused: GEMM1 (vposed) + GEMM2 (T) + epilogue ----------------
__global__ __launch_bounds__(256) void k_fused(const u16* __restrict__ A1,
                                               const u16* __restrict__ A2,
                                               const u16* __restrict__ WT,
                                               const u16* __restrict__ BT,
                                               const float* __restrict__ vt,
                                               const float* __restrict__ th,
                                               float* __restrict__ out){
    int t = threadIdx.x;
    int wave = t>>6, lane = t&63;
    int quad = lane>>4, l16 = lane&15;
    int m0 = blockIdx.x*32 + (wave&1)*16;
    int v0 = blockIdx.y*32 + (wave>>1)*16;
    f32x4 zz = {0.f,0.f,0.f,0.f};
    f32x4 accP[3]; accP[0]=zz; accP[1]=zz; accP[2]=zz;
    f32x4 accT[12];
    #pragma unroll
    for(int e=0;e<12;e++) accT[e]=zz;

    // phase 1: vposed - vt = [pf|sh] @ [posedirs|shapedirs]
    const u16* a1 = A1 + (size_t)(m0 + l16)*KP + quad*8;
    const u16* b0 = BT + ((size_t)0*NVP + v0 + l16)*KP + quad*8;
    const u16* b1 = BT + ((size_t)1*NVP + v0 + l16)*KP + quad*8;
    const u16* b2 = BT + ((size_t)2*NVP + v0 + l16)*KP + quad*8;
    #pragma unroll
    for(int k0=0;k0<KP;k0+=32){
        bf16x8 af = *(const bf16x8*)(a1 + k0);
        bf16x8 f0 = *(const bf16x8*)(b0 + k0);
        bf16x8 f1 = *(const bf16x8*)(b1 + k0);
        bf16x8 f2 = *(const bf16x8*)(b2 + k0);
        accP[0] = __builtin_amdgcn_mfma_f32_16x16x32_bf16(af, f0, accP[0], 0,0,0);
        accP[1] = __builtin_amdgcn_mfma_f32_16x16x32_bf16(af, f1, accP[1], 0,0,0);
        accP[2] = __builtin_amdgcn_mfma_f32_16x16x32_bf16(af, f2, accP[2], 0,0,0);
    }
    // phase 2: T[b][v][e] = sum_j G[b][j][e] * w[v][j]
    bf16x8 wf = *(const bf16x8*)(WT + (size_t)(v0 + l16)*K2 + quad*8);
    #pragma unroll
    for(int e=0;e<12;e++){
        bf16x8 gf = *(const bf16x8*)(A2 + ((size_t)e*BN + m0 + l16)*K2 + quad*8);
        accT[e] = __builtin_amdgcn_mfma_f32_16x16x32_bf16(gf, wf, accT[e], 0,0,0);
    }
    // epilogue: out = T_rot*(accP+vt) + T_t + Th    (C/D: col=lane&15, row=quad*4+r)
    int v = v0 + l16;
    if(v < NV){
        float vt0 = vt[v*3], vt1 = vt[v*3+1], vt2 = vt[v*3+2];
        #pragma unroll
        for(int r=0;r<4;r++){
            int b = m0 + quad*4 + r;
            float p0 = accP[0][r] + vt0;
            float p1 = accP[1][r] + vt1;
            float p2 = accP[2][r] + vt2;
            float o0 = fmaf(accT[0][r],p0, fmaf(accT[1][r],p1, fmaf(accT[2][r], p2, accT[3][r]))) + th[b*3+0];
            float o1 = fmaf(accT[4][r],p0, fmaf(accT[5][r],p1, fmaf(accT[6][r], p2, accT[7][r]))) + th[b*3+1];
            float o2 = fmaf(accT[8][r],p0, fmaf(accT[9][r],p1, fmaf(accT[10][r],p2, accT[11][r]))) + th[b*3+2];
            float* op = out + ((size_t)b*NV + v)*3;
            op[0]=o0; op[1]=o1; op[2]=o2;
        }
    }
}

// ---------------- fallback: round-2 fused k_main ----------------
__global__ __launch_bounds__(256) void k_main(const float* __restrict__ vt,
                                              const float* __restrict__ sd,
                                              const float* __restrict__ pd,
                                              const float* __restrict__ wts,
                                              const float* __restrict__ th,
                                              const float* __restrict__ shapes,
                                              const float* __restrict__ ws,
                                              float* __restrict__ out){
    __shared__ __align__(16) float pf_s[BB*PSTR];
    __shared__ __align__(16) float g_s[BB*288];
    __shared__ float th_s[BB*3];
    __shared__ float sh_s[BB*NS];
    int tid = threadIdx.x;
    int b0  = blockIdx.y * BB;
    int v   = blockIdx.x * TV + tid;

    for(int i=tid; i<BB*PSTR; i+=TV) pf_s[i] = ws[WS_PF + b0*PSTR + i];
    for(int i=tid; i<BB*288;  i+=TV) g_s[i]  = ws[WS_G  + b0*288  + i];
    if(tid<BB*3)  th_s[tid] = th[b0*3+tid];
    if(tid<BB*NS) sh_s[tid] = shapes[b0*NS+tid];
    __syncthreads();
    if(v>=NV) return;

    float sdv[30];
    {
        const float2* sp = (const float2*)(sd + (size_t)v*30);
        #pragma unroll
        for(int i=0;i<15;i++){ float2 s2 = sp[i]; sdv[2*i]=s2.x; sdv[2*i+1]=s2.y; }
    }
    float vt0=vt[v*3], vt1=vt[v*3+1], vt2=vt[v*3+2];
    float vp[BB][3];
    #pragma unroll
    for(int b=0;b<BB;b++){
        #pragma unroll
        for(int d=0;d<3;d++){
            float a = (d==0)?vt0:((d==1)?vt1:vt2);
            #pragma unroll
            for(int l=0;l<NS;l++) a = fmaf(sh_s[b*NS+l], sdv[d*10+l], a);
            vp[b][d]=a;
        }
    }
    const float* pcol = pd + (size_t)v*3;
    int p=0;
    for(; p<=NP-4; p+=4){
        float pdv[4][3];
        #pragma unroll
        for(int q=0;q<4;q++){
            size_t base = (size_t)(p+q)*(NV*3);
            pdv[q][0]=pcol[base]; pdv[q][1]=pcol[base+1]; pdv[q][2]=pcol[base+2];
        }
        #pragma unroll
        for(int b=0;b<BB;b++){
            float4 f = *(const float4*)&pf_s[b*PSTR+p];
            #pragma unroll
            for(int d=0;d<3;d++)
                vp[b][d] = fmaf(f.x,pdv[0][d], fmaf(f.y,pdv[1][d], fmaf(f.z,pdv[2][d], fmaf(f.w,pdv[3][d], vp[b][d]))));
        }
    }
    for(; p<NP; p++){
        size_t base=(size_t)p*(NV*3);
        float p0=pcol[base], p1=pcol[base+1], p2=pcol[base+2];
        #pragma unroll
        for(int b=0;b<BB;b++){
            float f = pf_s[b*PSTR+p];
            vp[b][0]=fmaf(f,p0,vp[b][0]); vp[b][1]=fmaf(f,p1,vp[b][1]); vp[b][2]=fmaf(f,p2,vp[b][2]);
        }
    }
    float w[24];
    {
        const float4* wp = (const float4*)(wts + (size_t)v*24);
        #pragma unroll
        for(int i=0;i<6;i++){
            float4 u = wp[i];
            w[i*4+0]=u.x; w[i*4+1]=u.y; w[i*4+2]=u.z; w[i*4+3]=u.w;
        }
    }
    #pragma unroll 1
    for(int b=0;b<BB;b++){
        float4 T0=make_float4(0.f,0.f,0.f,0.f), T1=T0, T2=T0;
        #pragma unroll
        for(int j=0;j<NJ;j++){
            float wj = w[j];
            const float4* g = (const float4*)&g_s[b*288 + j*12];
            float4 g0=g[0], g1=g[1], g2=g[2];
            T0.x=fmaf(wj,g0.x,T0.x); T0.y=fmaf(wj,g0.y,T0.y); T0.z=fmaf(wj,g0.z,T0.z); T0.w=fmaf(wj,g0.w,T0.w);
            T1.x=fmaf(wj,g1.x,T1.x); T1.y=fmaf(wj,g1.y,T1.y); T1.z=fmaf(wj,g1.z,T1.z); T1.w=fmaf(wj,g1.w,T1.w);
            T2.x=fmaf(wj,g2.x,T2.x); T2.y=fmaf(wj,g2.y,T2.y); T2.z=fmaf(wj,g2.z,T2.z); T2.w=fmaf(wj,g2.w,T2.w);
        }
        float x=vp[b][0], y=vp[b][1], z=vp[b][2];
        float ox = fmaf(T0.x,x, fmaf(T0.y,y, fmaf(T0.z,z, T0.w))) + th_s[b*3+0];
        float oy = fmaf(T1.x,x, fmaf(T1.y,y, fmaf(T1.z,z, T1.w))) + th_s[b*3+1];
        float oz = fmaf(T2.x,x, fmaf(T2.y,y, fmaf(T2.z,z, T2.w))) + th_s[b*3+2];
        size_t o = ((size_t)(b0+b)*NV + v)*3;
        out[o]=ox; out[o+1]=oy; out[o+2]=oz;
    }
}

extern "C" void kernel_launch(void* const* d_in, const int* in_sizes, int n_in,
                              void* d_out, int out_size, void* d_ws, size_t ws_size,
                              hipStream_t stream){
    const float* poses  = (const float*)d_in[0];
    const float* shapes = (const float*)d_in[1];
    const float* Rh     = (const float*)d_in[2];
    const float* Th     = (const float*)d_in[3];
    const float* vt     = (const float*)d_in[4];
    const float* sd     = (const float*)d_in[5];
    const float* pdirs  = (const float*)d_in[6];
    const float* jreg   = (const float*)d_in[7];
    const float* wts    = (const float*)d_in[8];
    float* ws  = (float*)d_ws;
    float* out = (float*)d_out;
    u16* u = (u16*)d_ws;
    int full = (ws_size >= FULL_NEED) ? 1 : 0;

    hipLaunchKernelGGL(k_jreg, dim3(NJ,8), dim3(256), 0, stream, jreg, vt, sd, ws);
    hipLaunchKernelGGL(k_chain, dim3(BN), dim3(64), 0, stream, poses, shapes, Rh, ws,
                       u + WS_A1, u + WS_A2, full);
    if(full){
        hipLaunchKernelGGL(k_conv, dim3(NPAD/64, KP/32), dim3(256), 0, stream,
                           pdirs, sd, u + WS_BT);
        hipLaunchKernelGGL(k_wconv, dim3(NVP/256), dim3(256), 0, stream, wts, u + WS_WT);
        hipLaunchKernelGGL(k_fused, dim3(BN/32, NVP/32), dim3(256), 0, stream,
                           u + WS_A1, u + WS_A2, u + WS_WT, u + WS_BT, vt, Th, out);
    } else {
        hipLaunchKernelGGL(k_main, dim3((NV+TV-1)/TV, BN/BB), dim3(256), 0, stream,
                           vt, sd, pdirs, wts, Th, shapes, ws, out);
    }
}

// Round 7
// 157.424 us; speedup vs baseline: 1.9858x; 1.0425x over previous
//
#include <hip/hip_runtime.h>

// SMPL forward, all I/O fp32. B=512, V=6890, J=24, NS=10, NP=207.
//
// Full path (ws >= 10.38MB), fragment-major bf16 layouts:
//  A1 [28][512][8]      : [pf|shapes] k-chunks
//  A2 [12][4][512][8]   : G[b][j][e] per element e, k=j chunks
//  WT [4][NVP][8]       : weights k=j chunks
//  BT [3][28][NVP][8]   : [posedirs|shapedirs] per component
//  k_fused: per wave: B frags held in regs, m-loop x4: GEMM1 + GEMM2 + epilogue
// Fallback (small ws): round-2 fused k_main.

#define BN 512
#define NV 6890
#define NVP 6912        // padded V (216 x 32)
#define NJ 24
#define NS 10
#define NP 207
#define PSTR 208
#define KP 224          // padded K for GEMM1 (207 pf + 10 shapes + 7 pad)
#define NPAD 20736      // 3*NVP
#define BB 8
#define TV 256

// fallback ws layout (float offsets)
#define WS_JSP 0                      // 24*8*33 = 6336
#define WS_G   6400                   // 512*288 (fallback only)
#define WS_PF  153856                 // 512*208 (fallback only)
// full-path u16 offsets (after JSP: 6400 floats = 12800 u16)
#define WS_A1  12800                  // 28*512*8  = 114688 -> 127488
#define WS_A2  127488                 // 12*4*512*8= 196608 -> 324096
#define WS_WT  324096                 // 4*6912*8  = 221184 -> 545280
#define WS_BT  545280                 // 3*28*6912*8 = 4644864 -> 5190144 u16
#define FULL_NEED ((size_t)10380288)

typedef unsigned short u16;
typedef short bf16x8 __attribute__((ext_vector_type(8)));
typedef float f32x4  __attribute__((ext_vector_type(4)));

__constant__ int c_par[NJ] = {-1,0,0,0,1,2,3,4,5,6,7,8,9,9,9,12,13,14,16,17,18,19,20,21};

__device__ __forceinline__ u16 f2bf(float f){
    union { float f; unsigned i; } x; x.f = f;
    unsigned r = x.i + 0x7fffu + ((x.i >> 16) & 1u);   // RNE
    return (u16)(r >> 16);
}

// ---------------- k_jreg: partial folds of J_regressor ----------------
__global__ __launch_bounds__(256) void k_jreg(const float* __restrict__ jreg,
                                              const float* __restrict__ vt,
                                              const float* __restrict__ sd,
                                              float* __restrict__ ws){
    int j = blockIdx.x, s = blockIdx.y;
    int tid = threadIdx.x;
    int v0 = s*864, v1 = min(NV, v0+864);
    float acc[33];
    #pragma unroll
    for(int k=0;k<33;k++) acc[k]=0.f;
    for(int v=v0+tid; v<v1; v+=256){
        float jr = jreg[j*NV+v];
        #pragma unroll
        for(int d=0;d<3;d++) acc[d] = fmaf(jr, vt[v*3+d], acc[d]);
        const float2* sp = (const float2*)(sd + (size_t)v*30);
        #pragma unroll
        for(int k=0;k<15;k++){
            float2 s2 = sp[k];
            acc[3+2*k]   = fmaf(jr, s2.x, acc[3+2*k]);
            acc[3+2*k+1] = fmaf(jr, s2.y, acc[3+2*k+1]);
        }
    }
    __shared__ float red[4][33];
    int lane = tid & 63, wv = tid >> 6;
    #pragma unroll
    for(int k=0;k<33;k++){
        float val = acc[k];
        #pragma unroll
        for(int off=32; off; off>>=1) val += __shfl_down(val, off, 64);
        if(lane==0) red[wv][k]=val;
    }
    __syncthreads();
    if(tid<33) ws[WS_JSP + (j*8+s)*33 + tid] = red[0][tid]+red[1][tid]+red[2][tid]+red[3][tid];
}

// ---------------- k_conv: build BT[d][chunk][v][8] bf16 ----------------
__global__ __launch_bounds__(256) void k_conv(const float* __restrict__ pd,
                                              const float* __restrict__ sd,
                                              u16* __restrict__ bt){
    __shared__ u16 tile[32][65];
    int t = threadIdx.x;
    int n0 = blockIdx.x * 64;
    int k0 = blockIdx.y * 32;
    int nl = t & 63, kb = (t>>6)*8;
    int n = n0 + nl;
    #pragma unroll
    for(int i=0;i<8;i++){
        int k = k0 + kb + i;
        float v = 0.f;
        if(n < NV*3){
            if(k < NP)           v = pd[(size_t)k*(NV*3) + n];
            else if(k < NP+NS)   v = sd[(size_t)(n/3)*30 + (n%3)*10 + (k-NP)];
        }
        tile[kb+i][nl] = f2bf(v);
    }
    __syncthreads();
    int nl2 = t >> 2, kc = t & 3;
    union { u16 s[8]; uint4 q; } u;
    #pragma unroll
    for(int i=0;i<8;i++) u.s[i] = tile[kc*8+i][nl2];
    int ng = n0 + nl2;
    int v = ng/3, d = ng%3;
    int chunk = (k0>>3) + kc;
    *(uint4*)(bt + (((size_t)d*28 + chunk)*NVP + v)*8) = u.q;
}

// ---------------- k_wconv: weights -> WT[chunk][v][8] bf16 ----------------
__global__ __launch_bounds__(256) void k_wconv(const float* __restrict__ wts,
                                               u16* __restrict__ wt){
    int v = blockIdx.x*256 + threadIdx.x;
    if(v >= NVP) return;
    union { u16 s[32]; uint4 q[4]; } u;
    #pragma unroll
    for(int j=0;j<24;j++) u.s[j] = (v<NV) ? f2bf(wts[(size_t)v*24+j]) : (u16)0;
    #pragma unroll
    for(int j=24;j<32;j++) u.s[j]=0;
    #pragma unroll
    for(int c=0;c<4;c++)
        *(uint4*)(wt + ((size_t)c*NVP + v)*8) = u.q[c];
}

// ---------------- k_chain: rodrigues + chain + G + A1/A2 emit ----------------
__global__ __launch_bounds__(64) void k_chain(const float* __restrict__ poses,
                                              const float* __restrict__ shapes,
                                              const float* __restrict__ Rh,
                                              float* __restrict__ ws,
                                              u16* __restrict__ a1,
                                              u16* __restrict__ a2,
                                              int full){
    int b = blockIdx.x;
    int t = threadIdx.x;
    __shared__ float R[25][9];
    __shared__ float sh[NS];
    __shared__ float js[792];
    __shared__ float jrest[NJ][3];
    __shared__ float rel[NJ][3];
    __shared__ float chR[NJ][9];
    __shared__ float chT[NJ][3];
    __shared__ float Gs[NJ][12];

    if(t<25){
        float x,y,z;
        if(t<24){ x=poses[b*72+t*3]; y=poses[b*72+t*3+1]; z=poses[b*72+t*3+2]; }
        else    { x=Rh[b*3];         y=Rh[b*3+1];         z=Rh[b*3+2]; }
        float ax=x+1e-8f, ay=y+1e-8f, az=z+1e-8f;
        float ang = sqrtf(ax*ax+ay*ay+az*az);
        float inv = 1.f/ang;
        float rx=x*inv, ry=y*inv, rz=z*inv;
        float s = sinf(ang), c = cosf(ang), oc = 1.f - c;
        R[t][0]=1.f+oc*(-rz*rz-ry*ry); R[t][1]=-s*rz+oc*(rx*ry);      R[t][2]= s*ry+oc*(rx*rz);
        R[t][3]= s*rz+oc*(rx*ry);      R[t][4]=1.f+oc*(-rz*rz-rx*rx); R[t][5]=-s*rx+oc*(ry*rz);
        R[t][6]=-s*ry+oc*(rx*rz);      R[t][7]= s*rx+oc*(ry*rz);      R[t][8]=1.f+oc*(-ry*ry-rx*rx);
    }
    if(t<NS) sh[t]=shapes[b*NS+t];
    for(int idx=t; idx<792; idx+=64){
        int j = idx/33, e = idx%33;
        float a = 0.f;
        #pragma unroll
        for(int s=0;s<8;s++) a += ws[WS_JSP + (j*8+s)*33 + e];
        js[idx]=a;
    }
    __syncthreads();

    // pose feature -> A1 (full, fragment-major) or ws PF (fallback)
    for(int idx=t; idx<KP; idx+=64){
        float v = 0.f;
        if(idx<NP){
            int j = 1 + idx/9, e = idx%9;
            v = R[j][e] - ((e==0||e==4||e==8)?1.f:0.f);
        } else if(idx<NP+NS) v = sh[idx-NP];
        if(full){ a1[(((size_t)(idx>>3))*BN + b)*8 + (idx&7)] = f2bf(v); }
        else if(idx<PSTR) ws[WS_PF + b*PSTR + idx] = (idx<NP)?v:0.f;
    }
    if(t<NJ){
        #pragma unroll
        for(int d=0;d<3;d++){
            float a = js[t*33 + d];
            #pragma unroll
            for(int l=0;l<NS;l++) a = fmaf(sh[l], js[t*33 + 3 + d*10 + l], a);
            jrest[t][d]=a;
        }
    }
    __syncthreads();
    if(t<NJ){
        int p = c_par[t];
        #pragma unroll
        for(int d=0;d<3;d++) rel[t][d] = (t==0) ? jrest[0][d] : jrest[t][d]-jrest[p][d];
    }
    __syncthreads();
    if(t<9) chR[0][t]=R[0][t];
    if(t<3) chT[0][t]=rel[0][t];
    __syncthreads();
    for(int i=1;i<NJ;i++){
        if(t<12){
            int r=t>>2, cc=t&3, p=c_par[i];
            if(cc<3){
                chR[i][r*3+cc] = chR[p][r*3+0]*R[i][0*3+cc] + chR[p][r*3+1]*R[i][1*3+cc] + chR[p][r*3+2]*R[i][2*3+cc];
            } else {
                chT[i][r] = chR[p][r*3+0]*rel[i][0] + chR[p][r*3+1]*rel[i][1] + chR[p][r*3+2]*rel[i][2] + chT[p][r];
            }
        }
        __syncthreads();
    }
    if(t<NJ){
        float rg[9];
        #pragma unroll
        for(int k=0;k<9;k++) rg[k]=R[24][k];
        float at[3];
        #pragma unroll
        for(int r=0;r<3;r++){
            float tj = chR[t][r*3+0]*jrest[t][0] + chR[t][r*3+1]*jrest[t][1] + chR[t][r*3+2]*jrest[t][2];
            at[r] = chT[t][r] - tj;
        }
        #pragma unroll
        for(int r=0;r<3;r++){
            #pragma unroll
            for(int cc=0;cc<3;cc++)
                Gs[t][r*4+cc] = rg[r*3+0]*chR[t][0*3+cc] + rg[r*3+1]*chR[t][1*3+cc] + rg[r*3+2]*chR[t][2*3+cc];
            Gs[t][r*4+3] = rg[r*3+0]*at[0] + rg[r*3+1]*at[1] + rg[r*3+2]*at[2];
        }
    }
    __syncthreads();
    if(full){
        // A2[e][chunk][b][8] = bf16(G[b][j=k][e]), pad k>=24 -> 0
        for(int idx=t; idx<12*32; idx+=64){
            int e = idx>>5, k = idx&31;
            float v = (k<NJ) ? Gs[k][e] : 0.f;
            a2[((((size_t)e*4)+(k>>3))*BN + b)*8 + (k&7)] = f2bf(v);
        }
    } else if(t<NJ){
        float* g = &ws[WS_G + b*288 + t*12];
        #pragma unroll
        for(int e=0;e<12;e++) g[e] = Gs[t][e];
    }
}

// ---------------- k_fused: B-resident GEMM1 + GEMM2 + epilogue ----------------
__global__ __launch_bounds__(256) void k_fused(const u16* __restrict__ A1,
                                               const u16* __restrict__ A2,
                                               const u16* __restrict__ WT,
                                               const u16* __restrict__ BT,
                                               const float* __restrict__ vt,
                                               const float* __restrict__ th,
                                               float* __restrict__ out){
    int t = threadIdx.x;
    int w = t>>6, lane = t&63;
    int quad = lane>>4, l16 = lane&15;
    int v = blockIdx.y*64 + w*16 + l16;

    // held fragments: B (3 comps x 7 k-slices), weights
    bf16x8 Bf[3][7];
    #pragma unroll
    for(int d=0;d<3;d++)
        #pragma unroll
        for(int s=0;s<7;s++)
            Bf[d][s] = *(const bf16x8*)(BT + (((size_t)d*28 + s*4 + quad)*NVP + v)*8);
    bf16x8 wf = *(const bf16x8*)(WT + ((size_t)quad*NVP + v)*8);
    float vt0=0.f, vt1=0.f, vt2=0.f;
    if(v<NV){ vt0=vt[v*3]; vt1=vt[v*3+1]; vt2=vt[v*3+2]; }
    f32x4 zz = {0.f,0.f,0.f,0.f};

    #pragma unroll
    for(int mi=0;mi<4;mi++){
        int m0 = blockIdx.x*64 + mi*16;
        int mrow = m0 + l16;
        f32x4 accP0=zz, accP1=zz, accP2=zz;
        #pragma unroll
        for(int s=0;s<7;s++){
            bf16x8 af = *(const bf16x8*)(A1 + (((size_t)s*4 + quad)*BN + mrow)*8);
            accP0 = __builtin_amdgcn_mfma_f32_16x16x32_bf16(af, Bf[0][s], accP0, 0,0,0);
            accP1 = __builtin_amdgcn_mfma_f32_16x16x32_bf16(af, Bf[1][s], accP1, 0,0,0);
            accP2 = __builtin_amdgcn_mfma_f32_16x16x32_bf16(af, Bf[2][s], accP2, 0,0,0);
        }
        f32x4 accT[12];
        #pragma unroll
        for(int e=0;e<12;e++){
            bf16x8 gf = *(const bf16x8*)(A2 + (((size_t)e*4 + quad)*BN + mrow)*8);
            accT[e] = __builtin_amdgcn_mfma_f32_16x16x32_bf16(gf, wf, zz, 0,0,0);
        }
        if(v < NV){
            #pragma unroll
            for(int r=0;r<4;r++){
                int b = m0 + quad*4 + r;
                float t0 = th[b*3+0], t1 = th[b*3+1], t2 = th[b*3+2];
                float p0 = accP0[r] + vt0;
                float p1 = accP1[r] + vt1;
                float p2 = accP2[r] + vt2;
                float o0 = fmaf(accT[0][r],p0, fmaf(accT[1][r],p1, fmaf(accT[2][r], p2, accT[3][r]))) + t0;
                float o1 = fmaf(accT[4][r],p0, fmaf(accT[5][r],p1, fmaf(accT[6][r], p2, accT[7][r]))) + t1;
                float o2 = fmaf(accT[8][r],p0, fmaf(accT[9][r],p1, fmaf(accT[10][r],p2, accT[11][r]))) + t2;
                float* op = out + ((size_t)b*NV + v)*3;
                op[0]=o0; op[1]=o1; op[2]=o2;
            }
        }
    }
}

// ---------------- fallback: round-2 fused k_main ----------------
__global__ __launch_bounds__(256) void k_main(const float* __restrict__ vt,
                                              const float* __restrict__ sd,
                                              const float* __restrict__ pd,
                                              const float* __restrict__ wts,
                                              const float* __restrict__ th,
                                              const float* __restrict__ shapes,
                                              const float* __restrict__ ws,
                                              float* __restrict__ out){
    __shared__ __align__(16) float pf_s[BB*PSTR];
    __shared__ __align__(16) float g_s[BB*288];
    __shared__ float th_s[BB*3];
    __shared__ float sh_s[BB*NS];
    int tid = threadIdx.x;
    int b0  = blockIdx.y * BB;
    int v   = blockIdx.x * TV + tid;

    for(int i=tid; i<BB*PSTR; i+=TV) pf_s[i] = ws[WS_PF + b0*PSTR + i];
    for(int i=tid; i<BB*288;  i+=TV) g_s[i]  = ws[WS_G  + b0*288  + i];
    if(tid<BB*3)  th_s[tid] = th[b0*3+tid];
    if(tid<BB*NS) sh_s[tid] = shapes[b0*NS+tid];
    __syncthreads();
    if(v>=NV) return;

    float sdv[30];
    {
        const float2* sp = (const float2*)(sd + (size_t)v*30);
        #pragma unroll
        for(int i=0;i<15;i++){ float2 s2 = sp[i]; sdv[2*i]=s2.x; sdv[2*i+1]=s2.y; }
    }
    float vt0=vt[v*3], vt1=vt[v*3+1], vt2=vt[v*3+2];
    float vp[BB][3];
    #pragma unroll
    for(int b=0;b<BB;b++){
        #pragma unroll
        for(int d=0;d<3;d++){
            float a = (d==0)?vt0:((d==1)?vt1:vt2);
            #pragma unroll
            for(int l=0;l<NS;l++) a = fmaf(sh_s[b*NS+l], sdv[d*10+l], a);
            vp[b][d]=a;
        }
    }
    const float* pcol = pd + (size_t)v*3;
    int p=0;
    for(; p<=NP-4; p+=4){
        float pdv[4][3];
        #pragma unroll
        for(int q=0;q<4;q++){
            size_t base = (size_t)(p+q)*(NV*3);
            pdv[q][0]=pcol[base]; pdv[q][1]=pcol[base+1]; pdv[q][2]=pcol[base+2];
        }
        #pragma unroll
        for(int b=0;b<BB;b++){
            float4 f = *(const float4*)&pf_s[b*PSTR+p];
            #pragma unroll
            for(int d=0;d<3;d++)
                vp[b][d] = fmaf(f.x,pdv[0][d], fmaf(f.y,pdv[1][d], fmaf(f.z,pdv[2][d], fmaf(f.w,pdv[3][d], vp[b][d]))));
        }
    }
    for(; p<NP; p++){
        size_t base=(size_t)p*(NV*3);
        float p0=pcol[base], p1=pcol[base+1], p2=pcol[base+2];
        #pragma unroll
        for(int b=0;b<BB;b++){
            float f = pf_s[b*PSTR+p];
            vp[b][0]=fmaf(f,p0,vp[b][0]); vp[b][1]=fmaf(f,p1,vp[b][1]); vp[b][2]=fmaf(f,p2,vp[b][2]);
        }
    }
    float w[24];
    {
        const float4* wp = (const float4*)(wts + (size_t)v*24);
        #pragma unroll
        for(int i=0;i<6;i++){
            float4 u = wp[i];
            w[i*4+0]=u.x; w[i*4+1]=u.y; w[i*4+2]=u.z; w[i*4+3]=u.w;
        }
    }
    #pragma unroll 1
    for(int b=0;b<BB;b++){
        float4 T0=make_float4(0.f,0.f,0.f,0.f), T1=T0, T2=T0;
        #pragma unroll
        for(int j=0;j<NJ;j++){
            float wj = w[j];
            const float4* g = (const float4*)&g_s[b*288 + j*12];
            float4 g0=g[0], g1=g[1], g2=g[2];
            T0.x=fmaf(wj,g0.x,T0.x); T0.y=fmaf(wj,g0.y,T0.y); T0.z=fmaf(wj,g0.z,T0.z); T0.w=fmaf(wj,g0.w,T0.w);
            T1.x=fmaf(wj,g1.x,T1.x); T1.y=fmaf(wj,g1.y,T1.y); T1.z=fmaf(wj,g1.z,T1.z); T1.w=fmaf(wj,g1.w,T1.w);
            T2.x=fmaf(wj,g2.x,T2.x); T2.y=fmaf(wj,g2.y,T2.y); T2.z=fmaf(wj,g2.z,T2.z); T2.w=fmaf(wj,g2.w,T2.w);
        }
        float x=vp[b][0], y=vp[b][1], z=vp[b][2];
        float ox = fmaf(T0.x,x, fmaf(T0.y,y, fmaf(T0.z,z, T0.w))) + th_s[b*3+0];
        float oy = fmaf(T1.x,x, fmaf(T1.y,y, fmaf(T1.z,z, T1.w))) + th_s[b*3+1];
        float oz = fmaf(T2.x,x, fmaf(T2.y,y, fmaf(T2.z,z, T2.w))) + th_s[b*3+2];
        size_t o = ((size_t)(b0+b)*NV + v)*3;
        out[o]=ox; out[o+1]=oy; out[o+2]=oz;
    }
}

extern "C" void kernel_launch(void* const* d_in, const int* in_sizes, int n_in,
                              void* d_out, int out_size, void* d_ws, size_t ws_size,
                              hipStream_t stream){
    const float* poses  = (const float*)d_in[0];
    const float* shapes = (const float*)d_in[1];
    const float* Rh     = (const float*)d_in[2];
    const float* Th     = (const float*)d_in[3];
    const float* vt     = (const float*)d_in[4];
    const float* sd     = (const float*)d_in[5];
    const float* pdirs  = (const float*)d_in[6];
    const float* jreg   = (const float*)d_in[7];
    const float* wts    = (const float*)d_in[8];
    float* ws  = (float*)d_ws;
    float* out = (float*)d_out;
    u16* u = (u16*)d_ws;
    int full = (ws_size >= FULL_NEED) ? 1 : 0;

    hipLaunchKernelGGL(k_jreg, dim3(NJ,8), dim3(256), 0, stream, jreg, vt, sd, ws);
    hipLaunchKernelGGL(k_chain, dim3(BN), dim3(64), 0, stream, poses, shapes, Rh, ws,
                       u + WS_A1, u + WS_A2, full);
    if(full){
        hipLaunchKernelGGL(k_conv, dim3(NPAD/64, KP/32), dim3(256), 0, stream,
                           pdirs, sd, u + WS_BT);
        hipLaunchKernelGGL(k_wconv, dim3(NVP/256), dim3(256), 0, stream, wts, u + WS_WT);
        hipLaunchKernelGGL(k_fused, dim3(BN/64, NVP/64), dim3(256), 0, stream,
                           u + WS_A1, u + WS_A2, u + WS_WT, u + WS_BT, vt, Th, out);
    } else {
        hipLaunchKernelGGL(k_main, dim3((NV+TV-1)/TV, BN/BB), dim3(256), 0, stream,
                           vt, sd, pdirs, wts, Th, shapes, ws, out);
    }
}

// Round 8
// 139.037 us; speedup vs baseline: 2.2484x; 1.1322x over previous
//
#include <hip/hip_runtime.h>

// SMPL forward, all I/O fp32. B=512, V=6890, J=24, NS=10, NP=207.
//
// Full path (ws >= 10.38MB), 3 launches:
//  k_prep : partitioned grid: [0,192) jreg partial folds; [192,2460) posedirs->BT bf16;
//           [2460,2487) weights->WT bf16
//  k_chain: Rodrigues + chain + G=rot*A; emits A1 (pf|shapes) + A2 (G) fragment-major bf16
//  k_fused: B-register-resident MFMA GEMM1+GEMM2 + fp32 epilogue -> out (m-loop x8)
// Fallback (small ws): round-2 fused k_main.

#define BN 512
#define NV 6890
#define NVP 6912        // padded V (216 x 32)
#define NJ 24
#define NS 10
#define NP 207
#define PSTR 208
#define KP 224          // padded K for GEMM1 (207 pf + 10 shapes + 7 pad)
#define NPAD 20736      // 3*NVP
#define BB 8
#define TV 256

// fallback ws layout (float offsets)
#define WS_JSP 0                      // 24*8*33 = 6336
#define WS_G   6400                   // 512*288 (fallback only)
#define WS_PF  153856                 // 512*208 (fallback only)
// full-path u16 offsets (after JSP: 6400 floats = 12800 u16)
#define WS_A1  12800                  // 28*512*8  = 114688 -> 127488
#define WS_A2  127488                 // 12*4*512*8= 196608 -> 324096
#define WS_WT  324096                 // 4*6912*8  = 221184 -> 545280
#define WS_BT  545280                 // 3*28*6912*8 = 4644864 -> 5190144 u16
#define FULL_NEED ((size_t)10380288)

typedef unsigned short u16;
typedef short bf16x8 __attribute__((ext_vector_type(8)));
typedef float f32x4  __attribute__((ext_vector_type(4)));

__constant__ int c_par[NJ] = {-1,0,0,0,1,2,3,4,5,6,7,8,9,9,9,12,13,14,16,17,18,19,20,21};

__device__ __forceinline__ u16 f2bf(float f){
    union { float f; unsigned i; } x; x.f = f;
    unsigned r = x.i + 0x7fffu + ((x.i >> 16) & 1u);   // RNE
    return (u16)(r >> 16);
}

// ---------------- k_prep: jreg partials (192) | BT conv (2268) | WT conv (27) ----------------
__global__ __launch_bounds__(256) void k_prep(const float* __restrict__ jreg,
                                              const float* __restrict__ vt,
                                              const float* __restrict__ sd,
                                              const float* __restrict__ pd,
                                              const float* __restrict__ wts,
                                              float* __restrict__ ws,
                                              u16* __restrict__ bt,
                                              u16* __restrict__ wt,
                                              int full){
    __shared__ __align__(16) float s_red[4][33];
    __shared__ __align__(16) u16 s_tile[32][65];
    int bid = blockIdx.x;
    int t = threadIdx.x;

    if(bid < 192){
        // ---- J_regressor partial folds ----
        int j = bid >> 3, s = bid & 7;
        int v0 = s*864, v1 = min(NV, v0+864);
        float acc[33];
        #pragma unroll
        for(int k=0;k<33;k++) acc[k]=0.f;
        for(int v=v0+t; v<v1; v+=256){
            float jr = jreg[j*NV+v];
            #pragma unroll
            for(int d=0;d<3;d++) acc[d] = fmaf(jr, vt[v*3+d], acc[d]);
            const float2* sp = (const float2*)(sd + (size_t)v*30);
            #pragma unroll
            for(int k=0;k<15;k++){
                float2 s2 = sp[k];
                acc[3+2*k]   = fmaf(jr, s2.x, acc[3+2*k]);
                acc[3+2*k+1] = fmaf(jr, s2.y, acc[3+2*k+1]);
            }
        }
        int lane = t & 63, wv = t >> 6;
        #pragma unroll
        for(int k=0;k<33;k++){
            float val = acc[k];
            #pragma unroll
            for(int off=32; off; off>>=1) val += __shfl_down(val, off, 64);
            if(lane==0) s_red[wv][k]=val;
        }
        __syncthreads();
        if(t<33) ws[WS_JSP + (j*8+s)*33 + t] = s_red[0][t]+s_red[1][t]+s_red[2][t]+s_red[3][t];
    } else if(bid < 2460){
        // ---- posedirs|shapedirs -> BT[d][chunk][v][8] bf16 ----
        if(!full) return;
        int bid2 = bid - 192;
        int n0 = (bid2 % 324) * 64;
        int k0 = (bid2 / 324) * 32;
        int nl = t & 63, kb = (t>>6)*8;
        int n = n0 + nl;
        #pragma unroll
        for(int i=0;i<8;i++){
            int k = k0 + kb + i;
            float v = 0.f;
            if(n < NV*3){
                if(k < NP)           v = pd[(size_t)k*(NV*3) + n];
                else if(k < NP+NS)   v = sd[(size_t)(n/3)*30 + (n%3)*10 + (k-NP)];
            }
            s_tile[kb+i][nl] = f2bf(v);
        }
        __syncthreads();
        int nl2 = t >> 2, kc = t & 3;
        union { u16 s[8]; uint4 q; } u;
        #pragma unroll
        for(int i=0;i<8;i++) u.s[i] = s_tile[kc*8+i][nl2];
        int ng = n0 + nl2;
        int v = ng/3, d = ng%3;
        int chunk = (k0>>3) + kc;
        *(uint4*)(bt + (((size_t)d*28 + chunk)*NVP + v)*8) = u.q;
    } else {
        // ---- weights -> WT[chunk][v][8] bf16 ----
        if(!full) return;
        int v = (bid - 2460)*256 + t;
        if(v >= NVP) return;
        union { u16 s[32]; uint4 q[4]; } u;
        #pragma unroll
        for(int j=0;j<24;j++) u.s[j] = (v<NV) ? f2bf(wts[(size_t)v*24+j]) : (u16)0;
        #pragma unroll
        for(int j=24;j<32;j++) u.s[j]=0;
        #pragma unroll
        for(int c=0;c<4;c++)
            *(uint4*)(wt + ((size_t)c*NVP + v)*8) = u.q[c];
    }
}

// ---------------- k_chain: rodrigues + chain + G + A1/A2 emit ----------------
__global__ __launch_bounds__(64) void k_chain(const float* __restrict__ poses,
                                              const float* __restrict__ shapes,
                                              const float* __restrict__ Rh,
                                              float* __restrict__ ws,
                                              u16* __restrict__ a1,
                                              u16* __restrict__ a2,
                                              int full){
    int b = blockIdx.x;
    int t = threadIdx.x;
    __shared__ float R[25][9];
    __shared__ float sh[NS];
    __shared__ float js[792];
    __shared__ float jrest[NJ][3];
    __shared__ float rel[NJ][3];
    __shared__ float chR[NJ][9];
    __shared__ float chT[NJ][3];
    __shared__ float Gs[NJ][12];

    if(t<25){
        float x,y,z;
        if(t<24){ x=poses[b*72+t*3]; y=poses[b*72+t*3+1]; z=poses[b*72+t*3+2]; }
        else    { x=Rh[b*3];         y=Rh[b*3+1];         z=Rh[b*3+2]; }
        float ax=x+1e-8f, ay=y+1e-8f, az=z+1e-8f;
        float ang = sqrtf(ax*ax+ay*ay+az*az);
        float inv = 1.f/ang;
        float rx=x*inv, ry=y*inv, rz=z*inv;
        float s = sinf(ang), c = cosf(ang), oc = 1.f - c;
        R[t][0]=1.f+oc*(-rz*rz-ry*ry); R[t][1]=-s*rz+oc*(rx*ry);      R[t][2]= s*ry+oc*(rx*rz);
        R[t][3]= s*rz+oc*(rx*ry);      R[t][4]=1.f+oc*(-rz*rz-rx*rx); R[t][5]=-s*rx+oc*(ry*rz);
        R[t][6]=-s*ry+oc*(rx*rz);      R[t][7]= s*rx+oc*(ry*rz);      R[t][8]=1.f+oc*(-ry*ry-rx*rx);
    }
    if(t<NS) sh[t]=shapes[b*NS+t];
    for(int idx=t; idx<792; idx+=64){
        int j = idx/33, e = idx%33;
        float a = 0.f;
        #pragma unroll
        for(int s=0;s<8;s++) a += ws[WS_JSP + (j*8+s)*33 + e];
        js[idx]=a;
    }
    __syncthreads();

    // pose feature -> A1 (full, fragment-major) or ws PF (fallback)
    for(int idx=t; idx<KP; idx+=64){
        float v = 0.f;
        if(idx<NP){
            int j = 1 + idx/9, e = idx%9;
            v = R[j][e] - ((e==0||e==4||e==8)?1.f:0.f);
        } else if(idx<NP+NS) v = sh[idx-NP];
        if(full){ a1[(((size_t)(idx>>3))*BN + b)*8 + (idx&7)] = f2bf(v); }
        else if(idx<PSTR) ws[WS_PF + b*PSTR + idx] = (idx<NP)?v:0.f;
    }
    if(t<NJ){
        #pragma unroll
        for(int d=0;d<3;d++){
            float a = js[t*33 + d];
            #pragma unroll
            for(int l=0;l<NS;l++) a = fmaf(sh[l], js[t*33 + 3 + d*10 + l], a);
            jrest[t][d]=a;
        }
    }
    __syncthreads();
    if(t<NJ){
        int p = c_par[t];
        #pragma unroll
        for(int d=0;d<3;d++) rel[t][d] = (t==0) ? jrest[0][d] : jrest[t][d]-jrest[p][d];
    }
    __syncthreads();
    if(t<9) chR[0][t]=R[0][t];
    if(t<3) chT[0][t]=rel[0][t];
    __syncthreads();
    for(int i=1;i<NJ;i++){
        if(t<12){
            int r=t>>2, cc=t&3, p=c_par[i];
            if(cc<3){
                chR[i][r*3+cc] = chR[p][r*3+0]*R[i][0*3+cc] + chR[p][r*3+1]*R[i][1*3+cc] + chR[p][r*3+2]*R[i][2*3+cc];
            } else {
                chT[i][r] = chR[p][r*3+0]*rel[i][0] + chR[p][r*3+1]*rel[i][1] + chR[p][r*3+2]*rel[i][2] + chT[p][r];
            }
        }
        __syncthreads();
    }
    if(t<NJ){
        float rg[9];
        #pragma unroll
        for(int k=0;k<9;k++) rg[k]=R[24][k];
        float at[3];
        #pragma unroll
        for(int r=0;r<3;r++){
            float tj = chR[t][r*3+0]*jrest[t][0] + chR[t][r*3+1]*jrest[t][1] + chR[t][r*3+2]*jrest[t][2];
            at[r] = chT[t][r] - tj;
        }
        #pragma unroll
        for(int r=0;r<3;r++){
            #pragma unroll
            for(int cc=0;cc<3;cc++)
                Gs[t][r*4+cc] = rg[r*3+0]*chR[t][0*3+cc] + rg[r*3+1]*chR[t][1*3+cc] + rg[r*3+2]*chR[t][2*3+cc];
            Gs[t][r*4+3] = rg[r*3+0]*at[0] + rg[r*3+1]*at[1] + rg[r*3+2]*at[2];
        }
    }
    __syncthreads();
    if(full){
        // A2[e][chunk][b][8] = bf16(G[b][j=k][e]), pad k>=24 -> 0
        for(int idx=t; idx<12*32; idx+=64){
            int e = idx>>5, k = idx&31;
            float v = (k<NJ) ? Gs[k][e] : 0.f;
            a2[((((size_t)e*4)+(k>>3))*BN + b)*8 + (k&7)] = f2bf(v);
        }
    } else if(t<NJ){
        float* g = &ws[WS_G + b*288 + t*12];
        #pragma unroll
        for(int e=0;e<12;e++) g[e] = Gs[t][e];
    }
}

// ---------------- k_fused: B-resident GEMM1 + GEMM2 + epilogue, m-loop x8 ----------------
__global__ __launch_bounds__(256) void k_fused(const u16* __restrict__ A1,
                                               const u16* __restrict__ A2,
                                               const u16* __restrict__ WT,
                                               const u16* __restrict__ BT,
                                               const float* __restrict__ vt,
                                               const float* __restrict__ th,
                                               float* __restrict__ out){
    int t = threadIdx.x;
    int w = t>>6, lane = t&63;
    int quad = lane>>4, l16 = lane&15;
    int v = blockIdx.y*64 + w*16 + l16;

    // held fragments: B (3 comps x 7 k-slices), weights
    bf16x8 Bf[3][7];
    #pragma unroll
    for(int d=0;d<3;d++)
        #pragma unroll
        for(int s=0;s<7;s++)
            Bf[d][s] = *(const bf16x8*)(BT + (((size_t)d*28 + s*4 + quad)*NVP + v)*8);
    bf16x8 wf = *(const bf16x8*)(WT + ((size_t)quad*NVP + v)*8);
    float vt0=0.f, vt1=0.f, vt2=0.f;
    if(v<NV){ vt0=vt[v*3]; vt1=vt[v*3+1]; vt2=vt[v*3+2]; }
    f32x4 zz = {0.f,0.f,0.f,0.f};

    #pragma unroll 1
    for(int mi=0;mi<8;mi++){
        int m0 = blockIdx.x*128 + mi*16;
        int mrow = m0 + l16;
        f32x4 accP0=zz, accP1=zz, accP2=zz;
        #pragma unroll
        for(int s=0;s<7;s++){
            bf16x8 af = *(const bf16x8*)(A1 + (((size_t)s*4 + quad)*BN + mrow)*8);
            accP0 = __builtin_amdgcn_mfma_f32_16x16x32_bf16(af, Bf[0][s], accP0, 0,0,0);
            accP1 = __builtin_amdgcn_mfma_f32_16x16x32_bf16(af, Bf[1][s], accP1, 0,0,0);
            accP2 = __builtin_amdgcn_mfma_f32_16x16x32_bf16(af, Bf[2][s], accP2, 0,0,0);
        }
        f32x4 accT[12];
        #pragma unroll
        for(int e=0;e<12;e++){
            bf16x8 gf = *(const bf16x8*)(A2 + (((size_t)e*4 + quad)*BN + mrow)*8);
            accT[e] = __builtin_amdgcn_mfma_f32_16x16x32_bf16(gf, wf, zz, 0,0,0);
        }
        if(v < NV){
            #pragma unroll
            for(int r=0;r<4;r++){
                int b = m0 + quad*4 + r;
                float t0 = th[b*3+0], t1 = th[b*3+1], t2 = th[b*3+2];
                float p0 = accP0[r] + vt0;
                float p1 = accP1[r] + vt1;
                float p2 = accP2[r] + vt2;
                float o0 = fmaf(accT[0][r],p0, fmaf(accT[1][r],p1, fmaf(accT[2][r], p2, accT[3][r]))) + t0;
                float o1 = fmaf(accT[4][r],p0, fmaf(accT[5][r],p1, fmaf(accT[6][r], p2, accT[7][r]))) + t1;
                float o2 = fmaf(accT[8][r],p0, fmaf(accT[9][r],p1, fmaf(accT[10][r],p2, accT[11][r]))) + t2;
                float* op = out + ((size_t)b*NV + v)*3;
                op[0]=o0; op[1]=o1; op[2]=o2;
            }
        }
    }
}

// ---------------- fallback: round-2 fused k_main ----------------
__global__ __launch_bounds__(256) void k_main(const float* __restrict__ vt,
                                              const float* __restrict__ sd,
                                              const float* __restrict__ pd,
                                              const float* __restrict__ wts,
                                              const float* __restrict__ th,
                                              const float* __restrict__ shapes,
                                              const float* __restrict__ ws,
                                              float* __restrict__ out){
    __shared__ __align__(16) float pf_s[BB*PSTR];
    __shared__ __align__(16) float g_s[BB*288];
    __shared__ float th_s[BB*3];
    __shared__ float sh_s[BB*NS];
    int tid = threadIdx.x;
    int b0  = blockIdx.y * BB;
    int v   = blockIdx.x * TV + tid;

    for(int i=tid; i<BB*PSTR; i+=TV) pf_s[i] = ws[WS_PF + b0*PSTR + i];
    for(int i=tid; i<BB*288;  i+=TV) g_s[i]  = ws[WS_G  + b0*288  + i];
    if(tid<BB*3)  th_s[tid] = th[b0*3+tid];
    if(tid<BB*NS) sh_s[tid] = shapes[b0*NS+tid];
    __syncthreads();
    if(v>=NV) return;

    float sdv[30];
    {
        const float2* sp = (const float2*)(sd + (size_t)v*30);
        #pragma unroll
        for(int i=0;i<15;i++){ float2 s2 = sp[i]; sdv[2*i]=s2.x; sdv[2*i+1]=s2.y; }
    }
    float vt0=vt[v*3], vt1=vt[v*3+1], vt2=vt[v*3+2];
    float vp[BB][3];
    #pragma unroll
    for(int b=0;b<BB;b++){
        #pragma unroll
        for(int d=0;d<3;d++){
            float a = (d==0)?vt0:((d==1)?vt1:vt2);
            #pragma unroll
            for(int l=0;l<NS;l++) a = fmaf(sh_s[b*NS+l], sdv[d*10+l], a);
            vp[b][d]=a;
        }
    }
    const float* pcol = pd + (size_t)v*3;
    int p=0;
    for(; p<=NP-4; p+=4){
        float pdv[4][3];
        #pragma unroll
        for(int q=0;q<4;q++){
            size_t base = (size_t)(p+q)*(NV*3);
            pdv[q][0]=pcol[base]; pdv[q][1]=pcol[base+1]; pdv[q][2]=pcol[base+2];
        }
        #pragma unroll
        for(int b=0;b<BB;b++){
            float4 f = *(const float4*)&pf_s[b*PSTR+p];
            #pragma unroll
            for(int d=0;d<3;d++)
                vp[b][d] = fmaf(f.x,pdv[0][d], fmaf(f.y,pdv[1][d], fmaf(f.z,pdv[2][d], fmaf(f.w,pdv[3][d], vp[b][d]))));
        }
    }
    for(; p<NP; p++){
        size_t base=(size_t)p*(NV*3);
        float p0=pcol[base], p1=pcol[base+1], p2=pcol[base+2];
        #pragma unroll
        for(int b=0;b<BB;b++){
            float f = pf_s[b*PSTR+p];
            vp[b][0]=fmaf(f,p0,vp[b][0]); vp[b][1]=fmaf(f,p1,vp[b][1]); vp[b][2]=fmaf(f,p2,vp[b][2]);
        }
    }
    float w[24];
    {
        const float4* wp = (const float4*)(wts + (size_t)v*24);
        #pragma unroll
        for(int i=0;i<6;i++){
            float4 u = wp[i];
            w[i*4+0]=u.x; w[i*4+1]=u.y; w[i*4+2]=u.z; w[i*4+3]=u.w;
        }
    }
    #pragma unroll 1
    for(int b=0;b<BB;b++){
        float4 T0=make_float4(0.f,0.f,0.f,0.f), T1=T0, T2=T0;
        #pragma unroll
        for(int j=0;j<NJ;j++){
            float wj = w[j];
            const float4* g = (const float4*)&g_s[b*288 + j*12];
            float4 g0=g[0], g1=g[1], g2=g[2];
            T0.x=fmaf(wj,g0.x,T0.x); T0.y=fmaf(wj,g0.y,T0.y); T0.z=fmaf(wj,g0.z,T0.z); T0.w=fmaf(wj,g0.w,T0.w);
            T1.x=fmaf(wj,g1.x,T1.x); T1.y=fmaf(wj,g1.y,T1.y); T1.z=fmaf(wj,g1.z,T1.z); T1.w=fmaf(wj,g1.w,T1.w);
            T2.x=fmaf(wj,g2.x,T2.x); T2.y=fmaf(wj,g2.y,T2.y); T2.z=fmaf(wj,g2.z,T2.z); T2.w=fmaf(wj,g2.w,T2.w);
        }
        float x=vp[b][0], y=vp[b][1], z=vp[b][2];
        float ox = fmaf(T0.x,x, fmaf(T0.y,y, fmaf(T0.z,z, T0.w))) + th_s[b*3+0];
        float oy = fmaf(T1.x,x, fmaf(T1.y,y, fmaf(T1.z,z, T1.w))) + th_s[b*3+1];
        float oz = fmaf(T2.x,x, fmaf(T2.y,y, fmaf(T2.z,z, T2.w))) + th_s[b*3+2];
        size_t o = ((size_t)(b0+b)*NV + v)*3;
        out[o]=ox; out[o+1]=oy; out[o+2]=oz;
    }
}

extern "C" void kernel_launch(void* const* d_in, const int* in_sizes, int n_in,
                              void* d_out, int out_size, void* d_ws, size_t ws_size,
                              hipStream_t stream){
    const float* poses  = (const float*)d_in[0];
    const float* shapes = (const float*)d_in[1];
    const float* Rh     = (const float*)d_in[2];
    const float* Th     = (const float*)d_in[3];
    const float* vt     = (const float*)d_in[4];
    const float* sd     = (const float*)d_in[5];
    const float* pdirs  = (const float*)d_in[6];
    const float* jreg   = (const float*)d_in[7];
    const float* wts    = (const float*)d_in[8];
    float* ws  = (float*)d_ws;
    float* out = (float*)d_out;
    u16* u = (u16*)d_ws;
    int full = (ws_size >= FULL_NEED) ? 1 : 0;

    hipLaunchKernelGGL(k_prep, dim3(2487), dim3(256), 0, stream,
                       jreg, vt, sd, pdirs, wts, ws, u + WS_BT, u + WS_WT, full);
    hipLaunchKernelGGL(k_chain, dim3(BN), dim3(64), 0, stream, poses, shapes, Rh, ws,
                       u + WS_A1, u + WS_A2, full);
    if(full){
        hipLaunchKernelGGL(k_fused, dim3(BN/128, NVP/64), dim3(256), 0, stream,
                           u + WS_A1, u + WS_A2, u + WS_WT, u + WS_BT, vt, Th, out);
    } else {
        hipLaunchKernelGGL(k_main, dim3((NV+TV-1)/TV, BN/BB), dim3(256), 0, stream,
                           vt, sd, pdirs, wts, Th, shapes, ws, out);
    }
}